// Round 3
// baseline (204.267 us; speedup 1.0000x reference)
//
#include <hip/hip_runtime.h>

// NonLocalBlock: B=4, C=256, Ci=128, H=W=64, N=4096.
// R12: k_attn -> 64 i/wave (2 i-sets sharing every pv/gv LDS fragment read).
// R11 post-mortem: VALU cut didn't move dur; corrected cycle model shows
// MFMA32 ~32cyc/SIMD -> MfmaUtil 30% == 2 waves x 32 MFMA x 32 / 6.75K, with
// LDS pipe at ~61%: structure was 1 LDS read : 1 MFMA. Doubling i-per-wave
// halves LDS reads per work unit and doubles MFMA density. Grid 256 (1
// block/CU, 1 wave/SIMD, VGPR-unconstrained ~300); yP layout unchanged.
// All other kernels identical to R11.

#define B_  4
#define C_  256
#define CI  128
#define N_  4096
#define NB  (B_*N_)     // 16384
#define ISPLIT 16
#define MB_ (1u<<20)
#define LOG2E 1.442695041f

typedef _Float16 f16;
typedef f16   f16x8 __attribute__((ext_vector_type(8)));
typedef f16   f16x4 __attribute__((ext_vector_type(4)));
typedef float f32x4 __attribute__((ext_vector_type(4)));
typedef float f32x16 __attribute__((ext_vector_type(16)));
typedef unsigned u32x2 __attribute__((ext_vector_type(2)));
typedef unsigned u32x4v __attribute__((ext_vector_type(4)));

#define MFMA(a,b,c)   __builtin_amdgcn_mfma_f32_16x16x32_f16(a,b,c,0,0,0)
#define MFMA32(a,b,c) __builtin_amdgcn_mfma_f32_32x32x16_f16(a,b,c,0,0,0)

// async global->LDS, 16B per lane; LDS dest = wave-uniform base + lane*16
#define GLD16(g, lp) __builtin_amdgcn_global_load_lds( \
    (const __attribute__((address_space(1))) void*)(g), \
    (__attribute__((address_space(3))) void*)(lp), 16, 0, 0)

// ---- workspace byte offsets (~30 MB) ----
#define OFF_THETA  0                 // f16 [B][N][CI]  4 MB (pre-scaled by log2e)
#define OFF_PHI    (4u*MB_)          // f16 [B][N][CI]  4 MB
#define OFF_G      (8u*MB_)          // f16 [B][CI][N]  4 MB
#define OFF_YP     (12u*MB_)         // f16 [4][B][N][CI]  16 MB (j-quarter partials)
#define OFF_WY     0                 // f16 [B][C][N] 8 MB — overlays theta+phi (dead by k_wz)
#define OFF_MD     (28u*MB_)                  // f32 [NB]  -log2(D)  (64 KB)
#define OFF_PS     (OFF_MD + 65536)           // f32 [ISPLIT][NB]  1 MB
#define OFF_PSUM   (OFF_PS + ISPLIT*NB*4)     // f32 [256][2][256]  512 KB
#define OFF_SSUM   (OFF_PSUM + 524288)
#define OFF_SSQ    (OFF_SSUM + 1024)
#define OFF_WCVT   (OFF_SSQ + 1024)           // f16 weights g,t,p,z  256 KB
#define PSZ ((size_t)B_*N_*CI)

// ---------------- init: weight cvt f32->f16 ----------------
__global__ void k_init(const float* gw, const float* tw, const float* pw,
                       const float* zw, f16* wcvt) {
    int i = blockIdx.x * 256 + threadIdx.x;          // 0..131071
    const float* s;
    int which = i >> 15;
    if (which == 0) s = gw; else if (which == 1) s = tw;
    else if (which == 2) s = pw; else s = zw;
    wcvt[i] = (f16)s[i & 32767];
}

// ---------------- fused 1x1-conv projections (all 3, one x read) ----------------
__global__ __launch_bounds__(256) void k_proj(
        const float* __restrict__ x, const f16* __restrict__ wcvt,
        const float* __restrict__ gb, const float* __restrict__ tb,
        const float* __restrict__ pb,
        f16* __restrict__ thetaT, f16* __restrict__ phiT, f16* __restrict__ gC) {
    __shared__ __align__(16) f16 xT[32 * 264];       // [n][c], stride 264
    int bb = blockIdx.x >> 7;
    int n0 = (blockIdx.x & 127) * 32;
    int t = threadIdx.x;

    const float* xb = x + (size_t)bb * C_ * N_;
    for (int rep = 0; rep < 8; rep++) {
        int lin = rep * 256 + t;
        int c = lin >> 3, np = (lin & 7) * 4;
        float4 v = *reinterpret_cast<const float4*>(xb + c * N_ + n0 + np);
        xT[(np + 0) * 264 + c] = (f16)v.x;
        xT[(np + 1) * 264 + c] = (f16)v.y;
        xT[(np + 2) * 264 + c] = (f16)v.z;
        xT[(np + 3) * 264 + c] = (f16)v.w;
    }
    __syncthreads();

    int w = t >> 6, l16 = t & 15, q = (t & 63) >> 4;
    int ci0 = w * 32;
    for (int proj = 0; proj < 3; proj++) {
        const f16* W0 = wcvt + proj * 32768;         // [128][256] f16 row-major
        f32x4 acc[2][2] = {};
        for (int kk = 0; kk < 8; kk++) {
            f16x8 a0 = *reinterpret_cast<const f16x8*>(W0 + (ci0 + l16) * 256 + kk * 32 + q * 8);
            f16x8 a1 = *reinterpret_cast<const f16x8*>(W0 + (ci0 + 16 + l16) * 256 + kk * 32 + q * 8);
#pragma unroll
            for (int nt = 0; nt < 2; nt++) {
                f16x8 bv = *reinterpret_cast<const f16x8*>(&xT[(nt * 16 + l16) * 264 + kk * 32 + q * 8]);
                acc[0][nt] = MFMA(a0, bv, acc[0][nt]);
                acc[1][nt] = MFMA(a1, bv, acc[1][nt]);
            }
        }
        const float* bias = (proj == 0) ? gb : (proj == 1) ? tb : pb;
        float scl = (proj == 1) ? LOG2E : 1.0f;      // fold ln2 into theta
#pragma unroll
        for (int a = 0; a < 2; a++) {
#pragma unroll
            for (int nt = 0; nt < 2; nt++) {
                int n = n0 + nt * 16 + l16;
                int cib = ci0 + a * 16 + q * 4;
                if (proj == 0) {
#pragma unroll
                    for (int r = 0; r < 4; r++)
                        gC[((size_t)bb * CI + cib + r) * N_ + n] = (f16)(acc[a][nt][r] + bias[cib + r]);
                } else {
                    f16x4 v4;
#pragma unroll
                    for (int r = 0; r < 4; r++)
                        v4[r] = (f16)((acc[a][nt][r] + bias[cib + r]) * scl);
                    f16* dst = (proj == 1 ? thetaT : phiT) + ((size_t)bb * N_ + n) * CI + cib;
                    *reinterpret_cast<f16x4*>(dst) = v4;
                }
            }
        }
    }
}

// ---------------- pass 2: column exp-sums (32x32 swapped, lane-local j) ------
// grid 2048 = bb(4) x jb(32) x isp(16); i-slice 256 = 4 staged tiles of 64.
__global__ __launch_bounds__(256, 4) void k_cols(
        const f16* __restrict__ thetaT, const f16* __restrict__ phiT,
        float* __restrict__ ps) {
    __shared__ __align__(16) f16 thS[2][64 * 128];
    int id = blockIdx.x;                 // 2048
    int isp = id & 15, jb = (id >> 4) & 31, bb = id >> 9;
    int t = threadIdx.x, w = t >> 6, l = t & 63;
    int l31 = l & 31, hi = l >> 5;
    int jw = jb * 128 + w * 32 + l31;    // this lane's j column

    // phi B-frags: B[k][n=j], lane n=l31, k = kk*16 + hi*8 + e
    f16x8 pf[8];
    const f16* pb = phiT + ((size_t)bb * N_ + jw) * CI + hi * 8;
#pragma unroll
    for (int kk = 0; kk < 8; kk++)
        pf[kk] = *reinterpret_cast<const f16x8*>(pb + kk * 16);

    const f16* thB = thetaT + ((size_t)bb * N_ + isp * 256) * CI;
    auto stage = [&](int bf, int it0) {
#pragma unroll
        for (int r = 0; r < 4; r++) {
            int p = r * 256 + w * 64 + l;
            int pi = p >> 4, pu = (p & 15) ^ (pi & 15);
            const char* ga = (const char*)(thB + (size_t)(it0 + pi) * CI) + pu * 16;
            GLD16(ga, &thS[bf][(r * 256 + w * 64) * 8]);
        }
    };

    float s = 0.f;
    stage(0, 0);
    __syncthreads();
    for (int it = 0; it < 4; it++) {
        int bf = it & 1;
        if (it + 1 < 4) stage(bf ^ 1, (it + 1) * 64);
#pragma unroll
        for (int it2 = 0; it2 < 2; it2++) {
            f16x8 av[8];
#pragma unroll
            for (int kk = 0; kk < 8; kk++)
                av[kk] = *reinterpret_cast<const f16x8*>(
                    &thS[bf][(it2 * 32 + l31) * 128 + (((kk * 2 + hi) ^ (l31 & 15)) * 8)]);
            f32x16 f = {};
            __builtin_amdgcn_s_setprio(1);
#pragma unroll
            for (int kk = 0; kk < 8; kk++)
                f = MFMA32(av[kk], pf[kk], f);
            __builtin_amdgcn_s_setprio(0);
#pragma unroll
            for (int r = 0; r < 16; r++)
                s += __builtin_amdgcn_exp2f(f[r]);
        }
        __syncthreads();
    }
    s += __shfl_xor(s, 32);
    if (hi == 0)
        ps[isp * NB + bb * N_ + jw] = s;
}

// ---------------- merge: md[j] = -log2(sum_isp ps) ----------------
__global__ void k_colmerge(const float* __restrict__ ps, float* __restrict__ md) {
    int j = blockIdx.x * 256 + threadIdx.x;          // 0..16383
    float s = 0.f;
    for (int isp = 0; isp < ISPLIT; isp++) s += ps[isp * NB + j];
    md[j] = -__log2f(s);
}

// ---------------- pass 3: y = softmax(f) @ g  (swapped-QK 32x32, 64 i/wave) --
// grid 256 = jq(4) x bb(4) x ib(16); block = 4 waves x 64 i = 256 i.
// Each wave: 2 i-sets of 32; every pv/gv LDS fragment read feeds 2 MFMAs
// (halves LDS-read demand per work unit vs R11). 1 block/CU, 1 wave/SIMD,
// VGPR-unconstrained (~300). facc C-preloaded with -log2 D; exp2 direct;
// W A-frags via cvt_pkrtz + permlane32_swap (layouts identical to R10/R11).
__global__ __launch_bounds__(256, 1) void k_attn(
        const f16* __restrict__ thetaT, const f16* __restrict__ phiT,
        const f16* __restrict__ gC, const float* __restrict__ md,
        f16* __restrict__ yP) {
    __shared__ __align__(16) char smem[65536];
    f16 (*phiS)[64 * 128] = (f16(*)[64 * 128])smem;            // 2 x 16 KB [j][ci]
    f16 (*gS)[128 * 64]   = (f16(*)[128 * 64])(smem + 32768);  // 2 x 16 KB [ci][j]
    f16* yTr = (f16*)smem;                                     // epilogue overlay

    int jq = blockIdx.x & 3;
    int ib = blockIdx.x >> 2;          // 0..63
    int bb = ib >> 4;
    int i0 = (ib & 15) * 256;
    int t = threadIdx.x, w = t >> 6, l = t & 63;
    int l31 = l & 31, hi = l >> 5;
    int jbase = jq * 1024;

    // theta B-fragments, 2 i-sets: B[n=i][k]; lane n=l31, k=hi*8+e
    f16x8 ta[2][8];
#pragma unroll
    for (int is = 0; is < 2; is++) {
        const f16* tb = thetaT + ((size_t)bb * N_ + i0 + w * 64 + is * 32 + l31) * CI + hi * 8;
#pragma unroll
        for (int kk = 0; kk < 8; kk++)
            ta[is][kk] = *reinterpret_cast<const f16x8*>(tb + kk * 16);
    }

    const f16* phiB = phiT + (size_t)bb * N_ * CI;
    const f16* gB   = gC   + (size_t)bb * CI * N_;
    const float* mdb = md + bb * N_;

    auto stage = [&](int bf, int j0g) {
#pragma unroll
        for (int r = 0; r < 4; r++) {
            int p = r * 256 + w * 64 + l;
            int ub = (r * 256 + w * 64) * 8;          // wave-uniform LDS base (f16)
            int pj = p >> 4, pu = (p & 15) ^ (pj & 15);
            const char* ga = (const char*)(phiB + (size_t)(j0g + pj) * CI) + pu * 16;
            GLD16(ga, &phiS[bf][ub]);
            int pc = p >> 3, pu2 = (p & 7) ^ (pc & 7);
            const char* ga2 = (const char*)(gB + (size_t)pc * N_ + j0g) + pu2 * 16;
            GLD16(ga2, &gS[bf][ub]);
        }
    };

    f32x16 yacc[2][4] = {};              // [iset][cs]: y[i 32][ci = cs*32+l31]
    stage(0, jbase);
    __syncthreads();
    for (int jt = 0; jt < 16; jt++) {
        int bf = jt & 1;
        if (jt + 1 < 16) stage(bf ^ 1, jbase + (jt + 1) * 64);

        // facc init = -log2(D) (same for both i-sets; depends on j only)
        f32x16 facc[2][2];
#pragma unroll
        for (int js = 0; js < 2; js++)
#pragma unroll
            for (int c = 0; c < 4; c++) {
                float4 v = *reinterpret_cast<const float4*>(
                    mdb + jbase + jt * 64 + js * 32 + c * 8 + hi * 4);
                facc[0][js][c * 4 + 0] = v.x; facc[0][js][c * 4 + 1] = v.y;
                facc[0][js][c * 4 + 2] = v.z; facc[0][js][c * 4 + 3] = v.w;
                facc[1][js][c * 4 + 0] = v.x; facc[1][js][c * 4 + 1] = v.y;
                facc[1][js][c * 4 + 2] = v.z; facc[1][js][c * 4 + 3] = v.w;
            }

        // QK: each pv read feeds both i-sets (4 independent accumulator chains)
#pragma unroll
        for (int kk = 0; kk < 8; kk++) {
#pragma unroll
            for (int js = 0; js < 2; js++) {
                f16x8 pv = *reinterpret_cast<const f16x8*>(
                    &phiS[bf][(js * 32 + l31) * 128 + (((kk * 2 + hi) ^ (l31 & 15)) * 8)]);
                facc[0][js] = MFMA32(pv, ta[0][kk], facc[0][js]);
                facc[1][js] = MFMA32(pv, ta[1][kk], facc[1][js]);
            }
        }

        // softmax (exp2) + in-register relayout; each gv read feeds both i-sets
#pragma unroll
        for (int js = 0; js < 2; js++) {
#pragma unroll
            for (int ch = 0; ch < 2; ch++) {
                f16x8 wfr[2];
#pragma unroll
                for (int is = 0; is < 2; is++) {
                    float e0 = __builtin_amdgcn_exp2f(facc[is][js][ch * 8 + 0]);
                    float e1 = __builtin_amdgcn_exp2f(facc[is][js][ch * 8 + 1]);
                    float e2 = __builtin_amdgcn_exp2f(facc[is][js][ch * 8 + 2]);
                    float e3 = __builtin_amdgcn_exp2f(facc[is][js][ch * 8 + 3]);
                    float e4 = __builtin_amdgcn_exp2f(facc[is][js][ch * 8 + 4]);
                    float e5 = __builtin_amdgcn_exp2f(facc[is][js][ch * 8 + 5]);
                    float e6 = __builtin_amdgcn_exp2f(facc[is][js][ch * 8 + 6]);
                    float e7 = __builtin_amdgcn_exp2f(facc[is][js][ch * 8 + 7]);
                    unsigned p01 = __builtin_bit_cast(unsigned, __builtin_amdgcn_cvt_pkrtz(e0, e1));
                    unsigned p23 = __builtin_bit_cast(unsigned, __builtin_amdgcn_cvt_pkrtz(e2, e3));
                    unsigned p45 = __builtin_bit_cast(unsigned, __builtin_amdgcn_cvt_pkrtz(e4, e5));
                    unsigned p67 = __builtin_bit_cast(unsigned, __builtin_amdgcn_cvt_pkrtz(e6, e7));
                    u32x2 s0 = __builtin_amdgcn_permlane32_swap(p01, p45, false, false);
                    u32x2 s1 = __builtin_amdgcn_permlane32_swap(p23, p67, false, false);
                    u32x4v wu = {s0[0], s1[0], s0[1], s1[1]};
                    wfr[is] = __builtin_bit_cast(f16x8, wu);   // A[m=i=l31][k=hi*8+e]
                }
                int jc = js * 2 + ch;                          // 16-j chunk index
#pragma unroll
                for (int cs = 0; cs < 4; cs++) {
                    f16x8 gv = *reinterpret_cast<const f16x8*>(
                        &gS[bf][(cs * 32 + l31) * 64 + (((jc * 2 + hi) ^ (l31 & 7)) * 8)]);
                    yacc[0][cs] = MFMA32(wfr[0], gv, yacc[0][cs]);
                    yacc[1][cs] = MFMA32(wfr[1], gv, yacc[1][cs]);
                }
            }
        }
        __syncthreads();
    }

    // epilogue per i-set: yacc[is][cs][r] = y[i=(r&3)+8(r>>2)+4hi][ci=cs*32+l31]
#pragma unroll
    for (int is = 0; is < 2; is++) {
        f16* yw = yTr + w * (32 * 136);
#pragma unroll
        for (int cs = 0; cs < 4; cs++)
#pragma unroll
            for (int r = 0; r < 16; r++)
                yw[((r & 3) + 8 * (r >> 2) + 4 * hi) * 136 + cs * 32 + l31] = (f16)yacc[is][cs][r];
        f16* yo = yP + (size_t)jq * PSZ + ((size_t)bb * N_ + i0 + w * 64 + is * 32) * CI;
        __builtin_amdgcn_s_waitcnt(0);   // lgkm: yw writes visible to own wave
#pragma unroll
        for (int rr = 0; rr < 8; rr++) {
            int chunk = rr * 64 + l;
            int il = chunk >> 4, u = chunk & 15;
            *reinterpret_cast<f16x8*>(yo + il * CI + u * 8) =
                *reinterpret_cast<const f16x8*>(&yw[il * 136 + u * 8]);
        }
    }
}

// ---------------- pass 4: w_y = wz @ (sum of y partials) + b ----------------
// grid 256: block = bb(4) x nb(64 n-tiles of 64); reads its yP slice ONCE,
// computes all 256 output channels; per-block channel partials -> psum.
__global__ __launch_bounds__(256) void k_wz(
        const f16* __restrict__ wzc, const f16* __restrict__ yP,
        const float* __restrict__ zb, f16* __restrict__ wy,
        float* __restrict__ psum) {
    int id = blockIdx.x;                  // 256
    int nb = id & 63, bb = id >> 6;
    int t = threadIdx.x, w = t >> 6, l16 = t & 15, q = (t & 63) >> 4;
    int o0 = w * 64, n0 = nb * 64;
    f32x4 acc[4][4] = {};                 // [os][nt]
#pragma unroll
    for (int kk = 0; kk < 4; kk++) {
        f16x8 bv[4];
#pragma unroll
        for (int nt = 0; nt < 4; nt++) {
            size_t yi = ((size_t)bb * N_ + n0 + nt * 16 + l16) * CI + kk * 32 + q * 8;
            f16x8 b0 = *reinterpret_cast<const f16x8*>(yP + yi);
            f16x8 b1 = *reinterpret_cast<const f16x8*>(yP + PSZ + yi);
            f16x8 b2 = *reinterpret_cast<const f16x8*>(yP + 2 * PSZ + yi);
            f16x8 b3 = *reinterpret_cast<const f16x8*>(yP + 3 * PSZ + yi);
            bv[nt] = (b0 + b1) + (b2 + b3);
        }
#pragma unroll
        for (int os = 0; os < 4; os++) {
            f16x8 av = *reinterpret_cast<const f16x8*>(
                wzc + (o0 + os * 16 + l16) * CI + kk * 32 + q * 8);
#pragma unroll
            for (int nt = 0; nt < 4; nt++)
                acc[os][nt] = MFMA(av, bv[nt], acc[os][nt]);
        }
    }
#pragma unroll
    for (int os = 0; os < 4; os++)
#pragma unroll
    for (int r = 0; r < 4; r++) {
        int o = o0 + os * 16 + q * 4 + r;
        float bias = zb[o];
        float sr = 0.f, qr = 0.f;
#pragma unroll
        for (int nt = 0; nt < 4; nt++) {
            float v = acc[os][nt][r] + bias;
            wy[((size_t)bb * C_ + o) * N_ + n0 + nt * 16 + l16] = (f16)v;
            sr += v; qr += v * v;
        }
#pragma unroll
        for (int off = 1; off < 16; off <<= 1) {
            sr += __shfl_xor(sr, off);
            qr += __shfl_xor(qr, off);
        }
        if (l16 == 0) {
            psum[(o * 2 + 0) * 256 + id] = sr;
            psum[(o * 2 + 1) * 256 + id] = qr;
        }
    }
}

// ---------------- reduce psum -> ssum/ssq ----------------
__global__ void k_red(const float* __restrict__ psum, float* __restrict__ ssum,
                      float* __restrict__ ssq) {
    int b = blockIdx.x;                   // 0: ssum, 1: ssq
    int o = threadIdx.x;
    const float* src = psum + (o * 2 + b) * 256;
    float s = 0.f;
    for (int k = 0; k < 64; k++) {
        float4 v = reinterpret_cast<const float4*>(src)[k];
        s += v.x + v.y + v.z + v.w;
    }
    (b == 0 ? ssum : ssq)[o] = s;
}

// ---------------- pass 5: BN (stats inline) + residual ----------------
__global__ void k_final(const f16* __restrict__ wy, const float* __restrict__ x,
                        const float* __restrict__ ssum, const float* __restrict__ ssq,
                        const float* __restrict__ gamma, const float* __restrict__ beta,
                        float* __restrict__ out) {
    int p = blockIdx.x * 256 + threadIdx.x;           // 512K groups of 8
    int c = (p >> 9) & 255;
    const float inv = 1.0f / 16384.0f;
    float mean = ssum[c] * inv;
    float var = ssq[c] * inv - mean * mean;
    float s = gamma[c] * rsqrtf(var + 1e-5f);
    float h = beta[c] - mean * s;
    f16x8 wv = reinterpret_cast<const f16x8*>(wy)[p];
    float4 x0 = reinterpret_cast<const float4*>(x)[2 * p];
    float4 x1 = reinterpret_cast<const float4*>(x)[2 * p + 1];
    float4 o0, o1;
    o0.x = (float)wv[0] * s + h + x0.x;
    o0.y = (float)wv[1] * s + h + x0.y;
    o0.z = (float)wv[2] * s + h + x0.z;
    o0.w = (float)wv[3] * s + h + x0.w;
    o1.x = (float)wv[4] * s + h + x1.x;
    o1.y = (float)wv[5] * s + h + x1.y;
    o1.z = (float)wv[6] * s + h + x1.z;
    o1.w = (float)wv[7] * s + h + x1.w;
    reinterpret_cast<float4*>(out)[2 * p] = o0;
    reinterpret_cast<float4*>(out)[2 * p + 1] = o1;
}

extern "C" void kernel_launch(void* const* d_in, const int* in_sizes, int n_in,
                              void* d_out, int out_size, void* d_ws, size_t ws_size,
                              hipStream_t stream) {
    const float* x     = (const float*)d_in[0];
    const float* gw    = (const float*)d_in[1];
    const float* gb    = (const float*)d_in[2];
    const float* tw    = (const float*)d_in[3];
    const float* tbv   = (const float*)d_in[4];
    const float* pw    = (const float*)d_in[5];
    const float* pb    = (const float*)d_in[6];
    const float* zw    = (const float*)d_in[7];
    const float* zb    = (const float*)d_in[8];
    const float* gamma = (const float*)d_in[9];
    const float* beta  = (const float*)d_in[10];

    char* ws = (char*)d_ws;
    f16* thetaT = (f16*)(ws + OFF_THETA);
    f16* phiT   = (f16*)(ws + OFF_PHI);
    f16* gC     = (f16*)(ws + OFF_G);
    f16* yP     = (f16*)(ws + OFF_YP);
    f16* wy     = (f16*)(ws + OFF_WY);
    f16* wcvt   = (f16*)(ws + OFF_WCVT);
    float* md   = (float*)(ws + OFF_MD);
    float* ps   = (float*)(ws + OFF_PS);
    float* psum = (float*)(ws + OFF_PSUM);
    float* ssum = (float*)(ws + OFF_SSUM);
    float* ssq  = (float*)(ws + OFF_SSQ);

    k_init<<<512, 256, 0, stream>>>(gw, tw, pw, zw, wcvt);
    k_proj<<<512, 256, 0, stream>>>(x, wcvt, gb, tbv, pb, thetaT, phiT, gC);
    k_cols<<<2048, 256, 0, stream>>>(thetaT, phiT, ps);
    k_colmerge<<<64, 256, 0, stream>>>(ps, md);
    k_attn<<<256, 256, 0, stream>>>(thetaT, phiT, gC, md, yP);
    k_wz<<<256, 256, 0, stream>>>(wcvt + 3 * 32768, yP, zb, wy, psum);
    k_red<<<2, 256, 0, stream>>>(psum, ssum, ssq);
    k_final<<<2048, 256, 0, stream>>>(wy, x, ssum, ssq, gamma, beta, (float*)d_out);
}

// Round 4
// 203.694 us; speedup vs baseline: 1.0028x; 1.0028x over previous
//
#include <hip/hip_runtime.h>

// NonLocalBlock: B=4, C=256, Ci=128, H=W=64, N=4096.
// R13: k_attn = 512-thread block (8 waves, 2 waves/SIMD), wave pairs split the
// 64-j tile (js=w>>2) and each wave owns 64 i (iw=w&3, 2 i-sets): every pv/gv
// LDS read feeds 2 MFMAs AND occupancy stays 2 waves/SIMD. R12 post-mortem:
// per-unit-work the 64-i sharing was -31% (9.3K/2 vs 6.75K cyc), but 1
// wave/SIMD couldn't overlap the QK->softmax->PV chain. This geometry keeps
// both. Cross-pair yacc reduction via LDS once per block (amortized ~128
// cyc/jt). launch_bounds(512,2) pins regs <=256 (state ~224 + temps).
// All other kernels unchanged from R11.

#define B_  4
#define C_  256
#define CI  128
#define N_  4096
#define NB  (B_*N_)     // 16384
#define ISPLIT 16
#define MB_ (1u<<20)
#define LOG2E 1.442695041f

typedef _Float16 f16;
typedef f16   f16x8 __attribute__((ext_vector_type(8)));
typedef f16   f16x4 __attribute__((ext_vector_type(4)));
typedef float f32x4 __attribute__((ext_vector_type(4)));
typedef float f32x16 __attribute__((ext_vector_type(16)));
typedef unsigned u32x2 __attribute__((ext_vector_type(2)));
typedef unsigned u32x4v __attribute__((ext_vector_type(4)));

#define MFMA(a,b,c)   __builtin_amdgcn_mfma_f32_16x16x32_f16(a,b,c,0,0,0)
#define MFMA32(a,b,c) __builtin_amdgcn_mfma_f32_32x32x16_f16(a,b,c,0,0,0)

// async global->LDS, 16B per lane; LDS dest = wave-uniform base + lane*16
#define GLD16(g, lp) __builtin_amdgcn_global_load_lds( \
    (const __attribute__((address_space(1))) void*)(g), \
    (__attribute__((address_space(3))) void*)(lp), 16, 0, 0)

// ---- workspace byte offsets (~30 MB) ----
#define OFF_THETA  0                 // f16 [B][N][CI]  4 MB (pre-scaled by log2e)
#define OFF_PHI    (4u*MB_)          // f16 [B][N][CI]  4 MB
#define OFF_G      (8u*MB_)          // f16 [B][CI][N]  4 MB
#define OFF_YP     (12u*MB_)         // f16 [4][B][N][CI]  16 MB (j-quarter partials)
#define OFF_WY     0                 // f16 [B][C][N] 8 MB — overlays theta+phi (dead by k_wz)
#define OFF_MD     (28u*MB_)                  // f32 [NB]  -log2(D)  (64 KB)
#define OFF_PS     (OFF_MD + 65536)           // f32 [ISPLIT][NB]  1 MB
#define OFF_PSUM   (OFF_PS + ISPLIT*NB*4)     // f32 [256][2][256]  512 KB
#define OFF_SSUM   (OFF_PSUM + 524288)
#define OFF_SSQ    (OFF_SSUM + 1024)
#define OFF_WCVT   (OFF_SSQ + 1024)           // f16 weights g,t,p,z  256 KB
#define PSZ ((size_t)B_*N_*CI)

// ---------------- init: weight cvt f32->f16 ----------------
__global__ void k_init(const float* gw, const float* tw, const float* pw,
                       const float* zw, f16* wcvt) {
    int i = blockIdx.x * 256 + threadIdx.x;          // 0..131071
    const float* s;
    int which = i >> 15;
    if (which == 0) s = gw; else if (which == 1) s = tw;
    else if (which == 2) s = pw; else s = zw;
    wcvt[i] = (f16)s[i & 32767];
}

// ---------------- fused 1x1-conv projections (all 3, one x read) ----------------
__global__ __launch_bounds__(256) void k_proj(
        const float* __restrict__ x, const f16* __restrict__ wcvt,
        const float* __restrict__ gb, const float* __restrict__ tb,
        const float* __restrict__ pb,
        f16* __restrict__ thetaT, f16* __restrict__ phiT, f16* __restrict__ gC) {
    __shared__ __align__(16) f16 xT[32 * 264];       // [n][c], stride 264
    int bb = blockIdx.x >> 7;
    int n0 = (blockIdx.x & 127) * 32;
    int t = threadIdx.x;

    const float* xb = x + (size_t)bb * C_ * N_;
    for (int rep = 0; rep < 8; rep++) {
        int lin = rep * 256 + t;
        int c = lin >> 3, np = (lin & 7) * 4;
        float4 v = *reinterpret_cast<const float4*>(xb + c * N_ + n0 + np);
        xT[(np + 0) * 264 + c] = (f16)v.x;
        xT[(np + 1) * 264 + c] = (f16)v.y;
        xT[(np + 2) * 264 + c] = (f16)v.z;
        xT[(np + 3) * 264 + c] = (f16)v.w;
    }
    __syncthreads();

    int w = t >> 6, l16 = t & 15, q = (t & 63) >> 4;
    int ci0 = w * 32;
    for (int proj = 0; proj < 3; proj++) {
        const f16* W0 = wcvt + proj * 32768;         // [128][256] f16 row-major
        f32x4 acc[2][2] = {};
        for (int kk = 0; kk < 8; kk++) {
            f16x8 a0 = *reinterpret_cast<const f16x8*>(W0 + (ci0 + l16) * 256 + kk * 32 + q * 8);
            f16x8 a1 = *reinterpret_cast<const f16x8*>(W0 + (ci0 + 16 + l16) * 256 + kk * 32 + q * 8);
#pragma unroll
            for (int nt = 0; nt < 2; nt++) {
                f16x8 bv = *reinterpret_cast<const f16x8*>(&xT[(nt * 16 + l16) * 264 + kk * 32 + q * 8]);
                acc[0][nt] = MFMA(a0, bv, acc[0][nt]);
                acc[1][nt] = MFMA(a1, bv, acc[1][nt]);
            }
        }
        const float* bias = (proj == 0) ? gb : (proj == 1) ? tb : pb;
        float scl = (proj == 1) ? LOG2E : 1.0f;      // fold ln2 into theta
#pragma unroll
        for (int a = 0; a < 2; a++) {
#pragma unroll
            for (int nt = 0; nt < 2; nt++) {
                int n = n0 + nt * 16 + l16;
                int cib = ci0 + a * 16 + q * 4;
                if (proj == 0) {
#pragma unroll
                    for (int r = 0; r < 4; r++)
                        gC[((size_t)bb * CI + cib + r) * N_ + n] = (f16)(acc[a][nt][r] + bias[cib + r]);
                } else {
                    f16x4 v4;
#pragma unroll
                    for (int r = 0; r < 4; r++)
                        v4[r] = (f16)((acc[a][nt][r] + bias[cib + r]) * scl);
                    f16* dst = (proj == 1 ? thetaT : phiT) + ((size_t)bb * N_ + n) * CI + cib;
                    *reinterpret_cast<f16x4*>(dst) = v4;
                }
            }
        }
    }
}

// ---------------- pass 2: column exp-sums (32x32 swapped, lane-local j) ------
// grid 2048 = bb(4) x jb(32) x isp(16); i-slice 256 = 4 staged tiles of 64.
__global__ __launch_bounds__(256, 4) void k_cols(
        const f16* __restrict__ thetaT, const f16* __restrict__ phiT,
        float* __restrict__ ps) {
    __shared__ __align__(16) f16 thS[2][64 * 128];
    int id = blockIdx.x;                 // 2048
    int isp = id & 15, jb = (id >> 4) & 31, bb = id >> 9;
    int t = threadIdx.x, w = t >> 6, l = t & 63;
    int l31 = l & 31, hi = l >> 5;
    int jw = jb * 128 + w * 32 + l31;    // this lane's j column

    // phi B-frags: B[k][n=j], lane n=l31, k = kk*16 + hi*8 + e
    f16x8 pf[8];
    const f16* pb = phiT + ((size_t)bb * N_ + jw) * CI + hi * 8;
#pragma unroll
    for (int kk = 0; kk < 8; kk++)
        pf[kk] = *reinterpret_cast<const f16x8*>(pb + kk * 16);

    const f16* thB = thetaT + ((size_t)bb * N_ + isp * 256) * CI;
    auto stage = [&](int bf, int it0) {
#pragma unroll
        for (int r = 0; r < 4; r++) {
            int p = r * 256 + w * 64 + l;
            int pi = p >> 4, pu = (p & 15) ^ (pi & 15);
            const char* ga = (const char*)(thB + (size_t)(it0 + pi) * CI) + pu * 16;
            GLD16(ga, &thS[bf][(r * 256 + w * 64) * 8]);
        }
    };

    float s = 0.f;
    stage(0, 0);
    __syncthreads();
    for (int it = 0; it < 4; it++) {
        int bf = it & 1;
        if (it + 1 < 4) stage(bf ^ 1, (it + 1) * 64);
#pragma unroll
        for (int it2 = 0; it2 < 2; it2++) {
            f16x8 av[8];
#pragma unroll
            for (int kk = 0; kk < 8; kk++)
                av[kk] = *reinterpret_cast<const f16x8*>(
                    &thS[bf][(it2 * 32 + l31) * 128 + (((kk * 2 + hi) ^ (l31 & 15)) * 8)]);
            f32x16 f = {};
            __builtin_amdgcn_s_setprio(1);
#pragma unroll
            for (int kk = 0; kk < 8; kk++)
                f = MFMA32(av[kk], pf[kk], f);
            __builtin_amdgcn_s_setprio(0);
#pragma unroll
            for (int r = 0; r < 16; r++)
                s += __builtin_amdgcn_exp2f(f[r]);
        }
        __syncthreads();
    }
    s += __shfl_xor(s, 32);
    if (hi == 0)
        ps[isp * NB + bb * N_ + jw] = s;
}

// ---------------- merge: md[j] = -log2(sum_isp ps) ----------------
__global__ void k_colmerge(const float* __restrict__ ps, float* __restrict__ md) {
    int j = blockIdx.x * 256 + threadIdx.x;          // 0..16383
    float s = 0.f;
    for (int isp = 0; isp < ISPLIT; isp++) s += ps[isp * NB + j];
    md[j] = -__log2f(s);
}

// ---------------- pass 3: y = softmax(f) @ g  (8 waves, pair-split j, 64 i/wave) --
// grid 256 = jq(4) x bb(4) x ib(16); block = 512 threads covering 256 i.
// Wave w: js = w>>2 (32-j half), iw = w&3 (64-i block, 2 i-sets of 32).
// Per wave per jt: 16 QK + 16 PV MFMA32, only 16 LDS reads (each feeds 2).
// Cross-pair yacc reduction via LDS after the jt loop; js=0 waves write yP.
__global__ __launch_bounds__(512, 2) void k_attn(
        const f16* __restrict__ thetaT, const f16* __restrict__ phiT,
        const f16* __restrict__ gC, const float* __restrict__ md,
        f16* __restrict__ yP) {
    __shared__ __align__(16) char smem[65536];
    f16 (*phiS)[64 * 128] = (f16(*)[64 * 128])smem;            // 2 x 16 KB [j][ci]
    f16 (*gS)[128 * 64]   = (f16(*)[128 * 64])(smem + 32768);  // 2 x 16 KB [ci][j]

    int jq = blockIdx.x & 3;
    int ib = blockIdx.x >> 2;          // 0..63
    int bb = ib >> 4;
    int i0 = (ib & 15) * 256;
    int t = threadIdx.x, w = t >> 6, l = t & 63;
    int l31 = l & 31, hi = l >> 5;
    int js = w >> 2, iw = w & 3;
    int jbase = jq * 1024;

    // theta B-fragments, 2 i-sets of 32: B[n=i][k]; lane n=l31, k=hi*8+e
    f16x8 ta[2][8];
#pragma unroll
    for (int is = 0; is < 2; is++) {
        const f16* tb = thetaT + ((size_t)bb * N_ + i0 + iw * 64 + is * 32 + l31) * CI + hi * 8;
#pragma unroll
        for (int kk = 0; kk < 8; kk++)
            ta[is][kk] = *reinterpret_cast<const f16x8*>(tb + kk * 16);
    }

    const f16* phiB = phiT + (size_t)bb * N_ * CI;
    const f16* gB   = gC   + (size_t)bb * CI * N_;
    const float* mdb = md + bb * N_;

    // 512 threads: 2 GLD16 pairs per thread cover 64x128 phi + 128x64 g
    auto stage = [&](int bf, int j0g) {
#pragma unroll
        for (int r = 0; r < 2; r++) {
            int p = r * 512 + t;
            int ub = (r * 512 + w * 64) * 8;          // wave-uniform LDS base (f16)
            int pj = p >> 4, pu = (p & 15) ^ (pj & 15);
            const char* ga = (const char*)(phiB + (size_t)(j0g + pj) * CI) + pu * 16;
            GLD16(ga, &phiS[bf][ub]);
            int pc = p >> 3, pu2 = (p & 7) ^ (pc & 7);
            const char* ga2 = (const char*)(gB + (size_t)pc * N_ + j0g) + pu2 * 16;
            GLD16(ga2, &gS[bf][ub]);
        }
    };

    f32x16 yacc[2][4] = {};              // [iset][cs]: y[i 32][ci = cs*32+l31]
    stage(0, jbase);
    __syncthreads();
    for (int jt = 0; jt < 16; jt++) {
        int bf = jt & 1;
        if (jt + 1 < 16) stage(bf ^ 1, jbase + (jt + 1) * 64);

        // facc init = -log2(D) for this wave's js half (j-dependent only)
        f32x16 facc[2];
#pragma unroll
        for (int c = 0; c < 4; c++) {
            float4 v = *reinterpret_cast<const float4*>(
                mdb + jbase + jt * 64 + js * 32 + c * 8 + hi * 4);
            facc[0][c * 4 + 0] = v.x; facc[0][c * 4 + 1] = v.y;
            facc[0][c * 4 + 2] = v.z; facc[0][c * 4 + 3] = v.w;
            facc[1][c * 4 + 0] = v.x; facc[1][c * 4 + 1] = v.y;
            facc[1][c * 4 + 2] = v.z; facc[1][c * 4 + 3] = v.w;
        }

        // QK: each pv read feeds both i-sets
        __builtin_amdgcn_s_setprio(1);
#pragma unroll
        for (int kk = 0; kk < 8; kk++) {
            f16x8 pv = *reinterpret_cast<const f16x8*>(
                &phiS[bf][(js * 32 + l31) * 128 + (((kk * 2 + hi) ^ (l31 & 15)) * 8)]);
            facc[0] = MFMA32(pv, ta[0][kk], facc[0]);
            facc[1] = MFMA32(pv, ta[1][kk], facc[1]);
        }
        __builtin_amdgcn_s_setprio(0);

        // softmax (exp2) + in-register relayout; each gv read feeds both i-sets
#pragma unroll
        for (int ch = 0; ch < 2; ch++) {
            f16x8 wfr[2];
#pragma unroll
            for (int is = 0; is < 2; is++) {
                float e0 = __builtin_amdgcn_exp2f(facc[is][ch * 8 + 0]);
                float e1 = __builtin_amdgcn_exp2f(facc[is][ch * 8 + 1]);
                float e2 = __builtin_amdgcn_exp2f(facc[is][ch * 8 + 2]);
                float e3 = __builtin_amdgcn_exp2f(facc[is][ch * 8 + 3]);
                float e4 = __builtin_amdgcn_exp2f(facc[is][ch * 8 + 4]);
                float e5 = __builtin_amdgcn_exp2f(facc[is][ch * 8 + 5]);
                float e6 = __builtin_amdgcn_exp2f(facc[is][ch * 8 + 6]);
                float e7 = __builtin_amdgcn_exp2f(facc[is][ch * 8 + 7]);
                unsigned p01 = __builtin_bit_cast(unsigned, __builtin_amdgcn_cvt_pkrtz(e0, e1));
                unsigned p23 = __builtin_bit_cast(unsigned, __builtin_amdgcn_cvt_pkrtz(e2, e3));
                unsigned p45 = __builtin_bit_cast(unsigned, __builtin_amdgcn_cvt_pkrtz(e4, e5));
                unsigned p67 = __builtin_bit_cast(unsigned, __builtin_amdgcn_cvt_pkrtz(e6, e7));
                u32x2 s0 = __builtin_amdgcn_permlane32_swap(p01, p45, false, false);
                u32x2 s1 = __builtin_amdgcn_permlane32_swap(p23, p67, false, false);
                u32x4v wu = {s0[0], s1[0], s0[1], s1[1]};
                wfr[is] = __builtin_bit_cast(f16x8, wu);   // A[m=i=l31][k=hi*8+e]
            }
            int jc = js * 2 + ch;                          // 16-j chunk index
            __builtin_amdgcn_s_setprio(1);
#pragma unroll
            for (int cs = 0; cs < 4; cs++) {
                f16x8 gv = *reinterpret_cast<const f16x8*>(
                    &gS[bf][(cs * 32 + l31) * 64 + (((jc * 2 + hi) ^ (l31 & 7)) * 8)]);
                yacc[0][cs] = MFMA32(wfr[0], gv, yacc[0][cs]);
                yacc[1][cs] = MFMA32(wfr[1], gv, yacc[1][cs]);
            }
            __builtin_amdgcn_s_setprio(0);
        }
        __syncthreads();
    }

    // ---- cross-pair reduction: js=1 partials -> js=0 waves, per i-set ----
    float* red = (float*)smem;            // [iw][cs][rq][lane][4] f32 = 64 KB per i-set
#pragma unroll
    for (int is = 0; is < 2; is++) {
        __syncthreads();
        if (js == 1) {
#pragma unroll
            for (int cs = 0; cs < 4; cs++)
#pragma unroll
                for (int rq = 0; rq < 4; rq++) {
                    f32x4 v;
                    v[0] = yacc[is][cs][rq * 4 + 0];
                    v[1] = yacc[is][cs][rq * 4 + 1];
                    v[2] = yacc[is][cs][rq * 4 + 2];
                    v[3] = yacc[is][cs][rq * 4 + 3];
                    *reinterpret_cast<f32x4*>(&red[((iw * 4 + cs) * 4 + rq) * 256 + l * 4]) = v;
                }
        }
        __syncthreads();
        if (js == 0) {
#pragma unroll
            for (int cs = 0; cs < 4; cs++)
#pragma unroll
                for (int rq = 0; rq < 4; rq++) {
                    f32x4 v = *reinterpret_cast<const f32x4*>(
                        &red[((iw * 4 + cs) * 4 + rq) * 256 + l * 4]);
                    yacc[is][cs][rq * 4 + 0] += v[0];
                    yacc[is][cs][rq * 4 + 1] += v[1];
                    yacc[is][cs][rq * 4 + 2] += v[2];
                    yacc[is][cs][rq * 4 + 3] += v[3];
                }
        }
    }
    __syncthreads();

    // ---- epilogue (js=0 waves): transpose via per-wave LDS, store yP ----
    if (js == 0) {
        f16* yw = (f16*)smem + iw * (32 * 136);
#pragma unroll
        for (int is = 0; is < 2; is++) {
#pragma unroll
            for (int cs = 0; cs < 4; cs++)
#pragma unroll
                for (int r = 0; r < 16; r++)
                    yw[((r & 3) + 8 * (r >> 2) + 4 * hi) * 136 + cs * 32 + l31] =
                        (f16)yacc[is][cs][r];
            f16* yo = yP + (size_t)jq * PSZ + ((size_t)bb * N_ + i0 + iw * 64 + is * 32) * CI;
            __builtin_amdgcn_s_waitcnt(0);   // lgkm: yw writes visible to own wave
#pragma unroll
            for (int rr = 0; rr < 8; rr++) {
                int chunk = rr * 64 + l;
                int il = chunk >> 4, u = chunk & 15;
                *reinterpret_cast<f16x8*>(yo + il * CI + u * 8) =
                    *reinterpret_cast<const f16x8*>(&yw[il * 136 + u * 8]);
            }
            __builtin_amdgcn_s_waitcnt(0);   // drain reads before is=1 overwrites yw
        }
    }
}

// ---------------- pass 4: w_y = wz @ (sum of y partials) + b ----------------
// grid 256: block = bb(4) x nb(64 n-tiles of 64); reads its yP slice ONCE,
// computes all 256 output channels; per-block channel partials -> psum.
__global__ __launch_bounds__(256) void k_wz(
        const f16* __restrict__ wzc, const f16* __restrict__ yP,
        const float* __restrict__ zb, f16* __restrict__ wy,
        float* __restrict__ psum) {
    int id = blockIdx.x;                  // 256
    int nb = id & 63, bb = id >> 6;
    int t = threadIdx.x, w = t >> 6, l16 = t & 15, q = (t & 63) >> 4;
    int o0 = w * 64, n0 = nb * 64;
    f32x4 acc[4][4] = {};                 // [os][nt]
#pragma unroll
    for (int kk = 0; kk < 4; kk++) {
        f16x8 bv[4];
#pragma unroll
        for (int nt = 0; nt < 4; nt++) {
            size_t yi = ((size_t)bb * N_ + n0 + nt * 16 + l16) * CI + kk * 32 + q * 8;
            f16x8 b0 = *reinterpret_cast<const f16x8*>(yP + yi);
            f16x8 b1 = *reinterpret_cast<const f16x8*>(yP + PSZ + yi);
            f16x8 b2 = *reinterpret_cast<const f16x8*>(yP + 2 * PSZ + yi);
            f16x8 b3 = *reinterpret_cast<const f16x8*>(yP + 3 * PSZ + yi);
            bv[nt] = (b0 + b1) + (b2 + b3);
        }
#pragma unroll
        for (int os = 0; os < 4; os++) {
            f16x8 av = *reinterpret_cast<const f16x8*>(
                wzc + (o0 + os * 16 + l16) * CI + kk * 32 + q * 8);
#pragma unroll
            for (int nt = 0; nt < 4; nt++)
                acc[os][nt] = MFMA(av, bv[nt], acc[os][nt]);
        }
    }
#pragma unroll
    for (int os = 0; os < 4; os++)
#pragma unroll
    for (int r = 0; r < 4; r++) {
        int o = o0 + os * 16 + q * 4 + r;
        float bias = zb[o];
        float sr = 0.f, qr = 0.f;
#pragma unroll
        for (int nt = 0; nt < 4; nt++) {
            float v = acc[os][nt][r] + bias;
            wy[((size_t)bb * C_ + o) * N_ + n0 + nt * 16 + l16] = (f16)v;
            sr += v; qr += v * v;
        }
#pragma unroll
        for (int off = 1; off < 16; off <<= 1) {
            sr += __shfl_xor(sr, off);
            qr += __shfl_xor(qr, off);
        }
        if (l16 == 0) {
            psum[(o * 2 + 0) * 256 + id] = sr;
            psum[(o * 2 + 1) * 256 + id] = qr;
        }
    }
}

// ---------------- reduce psum -> ssum/ssq ----------------
__global__ void k_red(const float* __restrict__ psum, float* __restrict__ ssum,
                      float* __restrict__ ssq) {
    int b = blockIdx.x;                   // 0: ssum, 1: ssq
    int o = threadIdx.x;
    const float* src = psum + (o * 2 + b) * 256;
    float s = 0.f;
    for (int k = 0; k < 64; k++) {
        float4 v = reinterpret_cast<const float4*>(src)[k];
        s += v.x + v.y + v.z + v.w;
    }
    (b == 0 ? ssum : ssq)[o] = s;
}

// ---------------- pass 5: BN (stats inline) + residual ----------------
__global__ void k_final(const f16* __restrict__ wy, const float* __restrict__ x,
                        const float* __restrict__ ssum, const float* __restrict__ ssq,
                        const float* __restrict__ gamma, const float* __restrict__ beta,
                        float* __restrict__ out) {
    int p = blockIdx.x * 256 + threadIdx.x;           // 512K groups of 8
    int c = (p >> 9) & 255;
    const float inv = 1.0f / 16384.0f;
    float mean = ssum[c] * inv;
    float var = ssq[c] * inv - mean * mean;
    float s = gamma[c] * rsqrtf(var + 1e-5f);
    float h = beta[c] - mean * s;
    f16x8 wv = reinterpret_cast<const f16x8*>(wy)[p];
    float4 x0 = reinterpret_cast<const float4*>(x)[2 * p];
    float4 x1 = reinterpret_cast<const float4*>(x)[2 * p + 1];
    float4 o0, o1;
    o0.x = (float)wv[0] * s + h + x0.x;
    o0.y = (float)wv[1] * s + h + x0.y;
    o0.z = (float)wv[2] * s + h + x0.z;
    o0.w = (float)wv[3] * s + h + x0.w;
    o1.x = (float)wv[4] * s + h + x1.x;
    o1.y = (float)wv[5] * s + h + x1.y;
    o1.z = (float)wv[6] * s + h + x1.z;
    o1.w = (float)wv[7] * s + h + x1.w;
    reinterpret_cast<float4*>(out)[2 * p] = o0;
    reinterpret_cast<float4*>(out)[2 * p + 1] = o1;
}

extern "C" void kernel_launch(void* const* d_in, const int* in_sizes, int n_in,
                              void* d_out, int out_size, void* d_ws, size_t ws_size,
                              hipStream_t stream) {
    const float* x     = (const float*)d_in[0];
    const float* gw    = (const float*)d_in[1];
    const float* gb    = (const float*)d_in[2];
    const float* tw    = (const float*)d_in[3];
    const float* tbv   = (const float*)d_in[4];
    const float* pw    = (const float*)d_in[5];
    const float* pb    = (const float*)d_in[6];
    const float* zw    = (const float*)d_in[7];
    const float* zb    = (const float*)d_in[8];
    const float* gamma = (const float*)d_in[9];
    const float* beta  = (const float*)d_in[10];

    char* ws = (char*)d_ws;
    f16* thetaT = (f16*)(ws + OFF_THETA);
    f16* phiT   = (f16*)(ws + OFF_PHI);
    f16* gC     = (f16*)(ws + OFF_G);
    f16* yP     = (f16*)(ws + OFF_YP);
    f16* wy     = (f16*)(ws + OFF_WY);
    f16* wcvt   = (f16*)(ws + OFF_WCVT);
    float* md   = (float*)(ws + OFF_MD);
    float* ps   = (float*)(ws + OFF_PS);
    float* psum = (float*)(ws + OFF_PSUM);
    float* ssum = (float*)(ws + OFF_SSUM);
    float* ssq  = (float*)(ws + OFF_SSQ);

    k_init<<<512, 256, 0, stream>>>(gw, tw, pw, zw, wcvt);
    k_proj<<<512, 256, 0, stream>>>(x, wcvt, gb, tbv, pb, thetaT, phiT, gC);
    k_cols<<<2048, 256, 0, stream>>>(thetaT, phiT, ps);
    k_colmerge<<<64, 256, 0, stream>>>(ps, md);
    k_attn<<<256, 512, 0, stream>>>(thetaT, phiT, gC, md, yP);
    k_wz<<<256, 256, 0, stream>>>(wcvt + 3 * 32768, yP, zb, wy, psum);
    k_red<<<2, 256, 0, stream>>>(psum, ssum, ssq);
    k_final<<<2048, 256, 0, stream>>>(wy, x, ssum, ssq, gamma, beta, (float*)d_out);
}

// Round 6
// 197.704 us; speedup vs baseline: 1.0332x; 1.0303x over previous
//
#include <hip/hip_runtime.h>

// NonLocalBlock: B=4, C=256, Ci=128, H=W=64, N=4096.
// R15 = R14 with md-staging base fix (&mdL[w*256], was w*64: GLD16 writes
// lane*16B so a wave spans 1024B; overlap left mdL[320..1024) uninitialized
// -> exp2(garbage) -> NaN). Schedule unchanged: 3-buffer counted-vmcnt
// (stage(t+2); compute(t); s_waitcnt vmcnt(4); raw s_barrier — tile t+2
// in flight across the barrier, T3/T4). md slice pre-staged to LDS so
// in-loop md reads are lgkm-counted (no vmcnt pollution).
// All other kernels unchanged from R11.

#define B_  4
#define C_  256
#define CI  128
#define N_  4096
#define NB  (B_*N_)     // 16384
#define ISPLIT 16
#define MB_ (1u<<20)
#define LOG2E 1.442695041f

typedef _Float16 f16;
typedef f16   f16x8 __attribute__((ext_vector_type(8)));
typedef f16   f16x4 __attribute__((ext_vector_type(4)));
typedef float f32x4 __attribute__((ext_vector_type(4)));
typedef float f32x16 __attribute__((ext_vector_type(16)));
typedef unsigned u32x2 __attribute__((ext_vector_type(2)));
typedef unsigned u32x4v __attribute__((ext_vector_type(4)));

#define MFMA(a,b,c)   __builtin_amdgcn_mfma_f32_16x16x32_f16(a,b,c,0,0,0)
#define MFMA32(a,b,c) __builtin_amdgcn_mfma_f32_32x32x16_f16(a,b,c,0,0,0)

// async global->LDS, 16B per lane; LDS dest = wave-uniform base + lane*16
#define GLD16(g, lp) __builtin_amdgcn_global_load_lds( \
    (const __attribute__((address_space(1))) void*)(g), \
    (__attribute__((address_space(3))) void*)(lp), 16, 0, 0)

// ---- workspace byte offsets (~30 MB) ----
#define OFF_THETA  0                 // f16 [B][N][CI]  4 MB (pre-scaled by log2e)
#define OFF_PHI    (4u*MB_)          // f16 [B][N][CI]  4 MB
#define OFF_G      (8u*MB_)          // f16 [B][CI][N]  4 MB
#define OFF_YP     (12u*MB_)         // f16 [4][B][N][CI]  16 MB (j-quarter partials)
#define OFF_WY     0                 // f16 [B][C][N] 8 MB — overlays theta+phi (dead by k_wz)
#define OFF_MD     (28u*MB_)                  // f32 [NB]  -log2(D)  (64 KB)
#define OFF_PS     (OFF_MD + 65536)           // f32 [ISPLIT][NB]  1 MB
#define OFF_PSUM   (OFF_PS + ISPLIT*NB*4)     // f32 [256][2][256]  512 KB
#define OFF_SSUM   (OFF_PSUM + 524288)
#define OFF_SSQ    (OFF_SSUM + 1024)
#define OFF_WCVT   (OFF_SSQ + 1024)           // f16 weights g,t,p,z  256 KB
#define PSZ ((size_t)B_*N_*CI)

// ---------------- init: weight cvt f32->f16 ----------------
__global__ void k_init(const float* gw, const float* tw, const float* pw,
                       const float* zw, f16* wcvt) {
    int i = blockIdx.x * 256 + threadIdx.x;          // 0..131071
    const float* s;
    int which = i >> 15;
    if (which == 0) s = gw; else if (which == 1) s = tw;
    else if (which == 2) s = pw; else s = zw;
    wcvt[i] = (f16)s[i & 32767];
}

// ---------------- fused 1x1-conv projections (all 3, one x read) ----------------
__global__ __launch_bounds__(256) void k_proj(
        const float* __restrict__ x, const f16* __restrict__ wcvt,
        const float* __restrict__ gb, const float* __restrict__ tb,
        const float* __restrict__ pb,
        f16* __restrict__ thetaT, f16* __restrict__ phiT, f16* __restrict__ gC) {
    __shared__ __align__(16) f16 xT[32 * 264];       // [n][c], stride 264
    int bb = blockIdx.x >> 7;
    int n0 = (blockIdx.x & 127) * 32;
    int t = threadIdx.x;

    const float* xb = x + (size_t)bb * C_ * N_;
    for (int rep = 0; rep < 8; rep++) {
        int lin = rep * 256 + t;
        int c = lin >> 3, np = (lin & 7) * 4;
        float4 v = *reinterpret_cast<const float4*>(xb + c * N_ + n0 + np);
        xT[(np + 0) * 264 + c] = (f16)v.x;
        xT[(np + 1) * 264 + c] = (f16)v.y;
        xT[(np + 2) * 264 + c] = (f16)v.z;
        xT[(np + 3) * 264 + c] = (f16)v.w;
    }
    __syncthreads();

    int w = t >> 6, l16 = t & 15, q = (t & 63) >> 4;
    int ci0 = w * 32;
    for (int proj = 0; proj < 3; proj++) {
        const f16* W0 = wcvt + proj * 32768;         // [128][256] f16 row-major
        f32x4 acc[2][2] = {};
        for (int kk = 0; kk < 8; kk++) {
            f16x8 a0 = *reinterpret_cast<const f16x8*>(W0 + (ci0 + l16) * 256 + kk * 32 + q * 8);
            f16x8 a1 = *reinterpret_cast<const f16x8*>(W0 + (ci0 + 16 + l16) * 256 + kk * 32 + q * 8);
#pragma unroll
            for (int nt = 0; nt < 2; nt++) {
                f16x8 bv = *reinterpret_cast<const f16x8*>(&xT[(nt * 16 + l16) * 264 + kk * 32 + q * 8]);
                acc[0][nt] = MFMA(a0, bv, acc[0][nt]);
                acc[1][nt] = MFMA(a1, bv, acc[1][nt]);
            }
        }
        const float* bias = (proj == 0) ? gb : (proj == 1) ? tb : pb;
        float scl = (proj == 1) ? LOG2E : 1.0f;      // fold ln2 into theta
#pragma unroll
        for (int a = 0; a < 2; a++) {
#pragma unroll
            for (int nt = 0; nt < 2; nt++) {
                int n = n0 + nt * 16 + l16;
                int cib = ci0 + a * 16 + q * 4;
                if (proj == 0) {
#pragma unroll
                    for (int r = 0; r < 4; r++)
                        gC[((size_t)bb * CI + cib + r) * N_ + n] = (f16)(acc[a][nt][r] + bias[cib + r]);
                } else {
                    f16x4 v4;
#pragma unroll
                    for (int r = 0; r < 4; r++)
                        v4[r] = (f16)((acc[a][nt][r] + bias[cib + r]) * scl);
                    f16* dst = (proj == 1 ? thetaT : phiT) + ((size_t)bb * N_ + n) * CI + cib;
                    *reinterpret_cast<f16x4*>(dst) = v4;
                }
            }
        }
    }
}

// ---------------- pass 2: column exp-sums (32x32 swapped, lane-local j) ------
// grid 2048 = bb(4) x jb(32) x isp(16); i-slice 256 = 4 staged tiles of 64.
__global__ __launch_bounds__(256, 4) void k_cols(
        const f16* __restrict__ thetaT, const f16* __restrict__ phiT,
        float* __restrict__ ps) {
    __shared__ __align__(16) f16 thS[2][64 * 128];
    int id = blockIdx.x;                 // 2048
    int isp = id & 15, jb = (id >> 4) & 31, bb = id >> 9;
    int t = threadIdx.x, w = t >> 6, l = t & 63;
    int l31 = l & 31, hi = l >> 5;
    int jw = jb * 128 + w * 32 + l31;    // this lane's j column

    // phi B-frags: B[k][n=j], lane n=l31, k = kk*16 + hi*8 + e
    f16x8 pf[8];
    const f16* pb = phiT + ((size_t)bb * N_ + jw) * CI + hi * 8;
#pragma unroll
    for (int kk = 0; kk < 8; kk++)
        pf[kk] = *reinterpret_cast<const f16x8*>(pb + kk * 16);

    const f16* thB = thetaT + ((size_t)bb * N_ + isp * 256) * CI;
    auto stage = [&](int bf, int it0) {
#pragma unroll
        for (int r = 0; r < 4; r++) {
            int p = r * 256 + w * 64 + l;
            int pi = p >> 4, pu = (p & 15) ^ (pi & 15);
            const char* ga = (const char*)(thB + (size_t)(it0 + pi) * CI) + pu * 16;
            GLD16(ga, &thS[bf][(r * 256 + w * 64) * 8]);
        }
    };

    float s = 0.f;
    stage(0, 0);
    __syncthreads();
    for (int it = 0; it < 4; it++) {
        int bf = it & 1;
        if (it + 1 < 4) stage(bf ^ 1, (it + 1) * 64);
#pragma unroll
        for (int it2 = 0; it2 < 2; it2++) {
            f16x8 av[8];
#pragma unroll
            for (int kk = 0; kk < 8; kk++)
                av[kk] = *reinterpret_cast<const f16x8*>(
                    &thS[bf][(it2 * 32 + l31) * 128 + (((kk * 2 + hi) ^ (l31 & 15)) * 8)]);
            f32x16 f = {};
            __builtin_amdgcn_s_setprio(1);
#pragma unroll
            for (int kk = 0; kk < 8; kk++)
                f = MFMA32(av[kk], pf[kk], f);
            __builtin_amdgcn_s_setprio(0);
#pragma unroll
            for (int r = 0; r < 16; r++)
                s += __builtin_amdgcn_exp2f(f[r]);
        }
        __syncthreads();
    }
    s += __shfl_xor(s, 32);
    if (hi == 0)
        ps[isp * NB + bb * N_ + jw] = s;
}

// ---------------- merge: md[j] = -log2(sum_isp ps) ----------------
__global__ void k_colmerge(const float* __restrict__ ps, float* __restrict__ md) {
    int j = blockIdx.x * 256 + threadIdx.x;          // 0..16383
    float s = 0.f;
    for (int isp = 0; isp < ISPLIT; isp++) s += ps[isp * NB + j];
    md[j] = -__log2f(s);
}

// ---------------- pass 3: y = softmax(f) @ g  (counted-vmcnt 3-buffer) ------
// grid 256 = jq(4) x bb(4) x ib(16); block = 512 threads (8 waves) on 256 i.
// Wave w: js = w>>2 (32-j half), iw = w&3 (64-i block, 2 i-sets of 32).
// Schedule: stage(t+2) -> compute(t) -> s_waitcnt vmcnt(4) -> raw s_barrier;
// tile t+2's 4 loads/wave stay in flight across the barrier (T4). md slice
// (4 KB) pre-staged to LDS so in-loop md reads are lgkm (no vmcnt pollution).
__global__ __launch_bounds__(512, 2) void k_attn(
        const f16* __restrict__ thetaT, const f16* __restrict__ phiT,
        const f16* __restrict__ gC, const float* __restrict__ md,
        f16* __restrict__ yP) {
    __shared__ __align__(16) char smem[102400];      // 3x(16+16) KB tiles + 4 KB md
    f16 (*phiS)[64 * 128] = (f16(*)[64 * 128])smem;            // 3 x 16 KB [j][ci]
    f16 (*gS)[128 * 64]   = (f16(*)[128 * 64])(smem + 49152);  // 3 x 16 KB [ci][j]
    float* mdL = (float*)(smem + 98304);                       // [1024] -log2 D

    int jq = blockIdx.x & 3;
    int ib = blockIdx.x >> 2;          // 0..63
    int bb = ib >> 4;
    int i0 = (ib & 15) * 256;
    int t = threadIdx.x, w = t >> 6, l = t & 63;
    int l31 = l & 31, hi = l >> 5;
    int js = w >> 2, iw = w & 3;
    int jbase = jq * 1024;

    // theta B-fragments, 2 i-sets of 32: B[n=i][k]; lane n=l31, k=hi*8+e
    f16x8 ta[2][8];
#pragma unroll
    for (int is = 0; is < 2; is++) {
        const f16* tb = thetaT + ((size_t)bb * N_ + i0 + iw * 64 + is * 32 + l31) * CI + hi * 8;
#pragma unroll
        for (int kk = 0; kk < 8; kk++)
            ta[is][kk] = *reinterpret_cast<const f16x8*>(tb + kk * 16);
    }

    const f16* phiB = phiT + (size_t)bb * N_ * CI;
    const f16* gB   = gC   + (size_t)bb * CI * N_;
    const float* mdb = md + bb * N_;

    // 512 threads: 2 GLD16 pairs per thread cover 64x128 phi + 128x64 g
    auto stage = [&](int bf, int j0g) {
#pragma unroll
        for (int r = 0; r < 2; r++) {
            int p = r * 512 + t;
            int ub = (r * 512 + w * 64) * 8;          // wave-uniform LDS base (f16)
            int pj = p >> 4, pu = (p & 15) ^ (pj & 15);
            const char* ga = (const char*)(phiB + (size_t)(j0g + pj) * CI) + pu * 16;
            GLD16(ga, &phiS[bf][ub]);
            int pc = p >> 3, pu2 = (p & 7) ^ (pc & 7);
            const char* ga2 = (const char*)(gB + (size_t)pc * N_ + j0g) + pu2 * 16;
            GLD16(ga2, &gS[bf][ub]);
        }
    };

    // prologue: md slice (waves 0-3; wave w covers mdL[w*256 .. w*256+256))
    if (w < 4)
        GLD16((const char*)(mdb + jbase + t * 4), &mdL[w * 256]);
    stage(0, jbase);
    stage(1, jbase + 64);
    asm volatile("s_waitcnt vmcnt(4)" ::: "memory");
    __builtin_amdgcn_s_barrier();

    f32x16 yacc[2][4] = {};              // [iset][cs]: y[i 32][ci = cs*32+l31]
    for (int jt = 0; jt < 16; jt++) {
        int bf = jt % 3;
        if (jt + 2 < 16) stage((jt + 2) % 3, jbase + (jt + 2) * 64);

        // facc init = -log2(D) from LDS (j-dependent only; same for both i-sets)
        f32x16 facc[2];
#pragma unroll
        for (int c = 0; c < 4; c++) {
            f32x4 v = *reinterpret_cast<const f32x4*>(
                &mdL[jt * 64 + js * 32 + c * 8 + hi * 4]);
            facc[0][c * 4 + 0] = v[0]; facc[0][c * 4 + 1] = v[1];
            facc[0][c * 4 + 2] = v[2]; facc[0][c * 4 + 3] = v[3];
            facc[1][c * 4 + 0] = v[0]; facc[1][c * 4 + 1] = v[1];
            facc[1][c * 4 + 2] = v[2]; facc[1][c * 4 + 3] = v[3];
        }

        // QK: each pv read feeds both i-sets
        __builtin_amdgcn_s_setprio(1);
#pragma unroll
        for (int kk = 0; kk < 8; kk++) {
            f16x8 pv = *reinterpret_cast<const f16x8*>(
                &phiS[bf][(js * 32 + l31) * 128 + (((kk * 2 + hi) ^ (l31 & 15)) * 8)]);
            facc[0] = MFMA32(pv, ta[0][kk], facc[0]);
            facc[1] = MFMA32(pv, ta[1][kk], facc[1]);
        }
        __builtin_amdgcn_s_setprio(0);

        // softmax (exp2) + in-register relayout; each gv read feeds both i-sets
#pragma unroll
        for (int ch = 0; ch < 2; ch++) {
            f16x8 wfr[2];
#pragma unroll
            for (int is = 0; is < 2; is++) {
                float e0 = __builtin_amdgcn_exp2f(facc[is][ch * 8 + 0]);
                float e1 = __builtin_amdgcn_exp2f(facc[is][ch * 8 + 1]);
                float e2 = __builtin_amdgcn_exp2f(facc[is][ch * 8 + 2]);
                float e3 = __builtin_amdgcn_exp2f(facc[is][ch * 8 + 3]);
                float e4 = __builtin_amdgcn_exp2f(facc[is][ch * 8 + 4]);
                float e5 = __builtin_amdgcn_exp2f(facc[is][ch * 8 + 5]);
                float e6 = __builtin_amdgcn_exp2f(facc[is][ch * 8 + 6]);
                float e7 = __builtin_amdgcn_exp2f(facc[is][ch * 8 + 7]);
                unsigned p01 = __builtin_bit_cast(unsigned, __builtin_amdgcn_cvt_pkrtz(e0, e1));
                unsigned p23 = __builtin_bit_cast(unsigned, __builtin_amdgcn_cvt_pkrtz(e2, e3));
                unsigned p45 = __builtin_bit_cast(unsigned, __builtin_amdgcn_cvt_pkrtz(e4, e5));
                unsigned p67 = __builtin_bit_cast(unsigned, __builtin_amdgcn_cvt_pkrtz(e6, e7));
                u32x2 s0 = __builtin_amdgcn_permlane32_swap(p01, p45, false, false);
                u32x2 s1 = __builtin_amdgcn_permlane32_swap(p23, p67, false, false);
                u32x4v wu = {s0[0], s1[0], s0[1], s1[1]};
                wfr[is] = __builtin_bit_cast(f16x8, wu);   // A[m=i=l31][k=hi*8+e]
            }
            int jc = js * 2 + ch;                          // 16-j chunk index
            __builtin_amdgcn_s_setprio(1);
#pragma unroll
            for (int cs = 0; cs < 4; cs++) {
                f16x8 gv = *reinterpret_cast<const f16x8*>(
                    &gS[bf][(cs * 32 + l31) * 64 + (((jc * 2 + hi) ^ (l31 & 7)) * 8)]);
                yacc[0][cs] = MFMA32(wfr[0], gv, yacc[0][cs]);
                yacc[1][cs] = MFMA32(wfr[1], gv, yacc[1][cs]);
            }
            __builtin_amdgcn_s_setprio(0);
        }

        // counted wait: keep tile t+2 in flight (4 loads/wave); drain at tail
        if (jt < 14) { asm volatile("s_waitcnt vmcnt(4)" ::: "memory"); }
        else         { asm volatile("s_waitcnt vmcnt(0)" ::: "memory"); }
        __builtin_amdgcn_s_barrier();
    }

    // ---- cross-pair reduction: js=1 partials -> js=0 waves, per i-set ----
    float* red = (float*)smem;            // 64 KB overlay (buffers dead)
#pragma unroll
    for (int is = 0; is < 2; is++) {
        __syncthreads();
        if (js == 1) {
#pragma unroll
            for (int cs = 0; cs < 4; cs++)
#pragma unroll
                for (int rq = 0; rq < 4; rq++) {
                    f32x4 v;
                    v[0] = yacc[is][cs][rq * 4 + 0];
                    v[1] = yacc[is][cs][rq * 4 + 1];
                    v[2] = yacc[is][cs][rq * 4 + 2];
                    v[3] = yacc[is][cs][rq * 4 + 3];
                    *reinterpret_cast<f32x4*>(&red[((iw * 4 + cs) * 4 + rq) * 256 + l * 4]) = v;
                }
        }
        __syncthreads();
        if (js == 0) {
#pragma unroll
            for (int cs = 0; cs < 4; cs++)
#pragma unroll
                for (int rq = 0; rq < 4; rq++) {
                    f32x4 v = *reinterpret_cast<const f32x4*>(
                        &red[((iw * 4 + cs) * 4 + rq) * 256 + l * 4]);
                    yacc[is][cs][rq * 4 + 0] += v[0];
                    yacc[is][cs][rq * 4 + 1] += v[1];
                    yacc[is][cs][rq * 4 + 2] += v[2];
                    yacc[is][cs][rq * 4 + 3] += v[3];
                }
        }
    }
    __syncthreads();

    // ---- epilogue (js=0 waves): transpose via per-wave LDS, store yP ----
    if (js == 0) {
        f16* yw = (f16*)smem + iw * (32 * 136);
#pragma unroll
        for (int is = 0; is < 2; is++) {
#pragma unroll
            for (int cs = 0; cs < 4; cs++)
#pragma unroll
                for (int r = 0; r < 16; r++)
                    yw[((r & 3) + 8 * (r >> 2) + 4 * hi) * 136 + cs * 32 + l31] =
                        (f16)yacc[is][cs][r];
            f16* yo = yP + (size_t)jq * PSZ + ((size_t)bb * N_ + i0 + iw * 64 + is * 32) * CI;
            __builtin_amdgcn_s_waitcnt(0);   // lgkm: yw writes visible to own wave
#pragma unroll
            for (int rr = 0; rr < 8; rr++) {
                int chunk = rr * 64 + l;
                int il = chunk >> 4, u = chunk & 15;
                *reinterpret_cast<f16x8*>(yo + il * CI + u * 8) =
                    *reinterpret_cast<const f16x8*>(&yw[il * 136 + u * 8]);
            }
            __builtin_amdgcn_s_waitcnt(0);   // drain reads before is=1 overwrites yw
        }
    }
}

// ---------------- pass 4: w_y = wz @ (sum of y partials) + b ----------------
// grid 256: block = bb(4) x nb(64 n-tiles of 64); reads its yP slice ONCE,
// computes all 256 output channels; per-block channel partials -> psum.
__global__ __launch_bounds__(256) void k_wz(
        const f16* __restrict__ wzc, const f16* __restrict__ yP,
        const float* __restrict__ zb, f16* __restrict__ wy,
        float* __restrict__ psum) {
    int id = blockIdx.x;                  // 256
    int nb = id & 63, bb = id >> 6;
    int t = threadIdx.x, w = t >> 6, l16 = t & 15, q = (t & 63) >> 4;
    int o0 = w * 64, n0 = nb * 64;
    f32x4 acc[4][4] = {};                 // [os][nt]
#pragma unroll
    for (int kk = 0; kk < 4; kk++) {
        f16x8 bv[4];
#pragma unroll
        for (int nt = 0; nt < 4; nt++) {
            size_t yi = ((size_t)bb * N_ + n0 + nt * 16 + l16) * CI + kk * 32 + q * 8;
            f16x8 b0 = *reinterpret_cast<const f16x8*>(yP + yi);
            f16x8 b1 = *reinterpret_cast<const f16x8*>(yP + PSZ + yi);
            f16x8 b2 = *reinterpret_cast<const f16x8*>(yP + 2 * PSZ + yi);
            f16x8 b3 = *reinterpret_cast<const f16x8*>(yP + 3 * PSZ + yi);
            bv[nt] = (b0 + b1) + (b2 + b3);
        }
#pragma unroll
        for (int os = 0; os < 4; os++) {
            f16x8 av = *reinterpret_cast<const f16x8*>(
                wzc + (o0 + os * 16 + l16) * CI + kk * 32 + q * 8);
#pragma unroll
            for (int nt = 0; nt < 4; nt++)
                acc[os][nt] = MFMA(av, bv[nt], acc[os][nt]);
        }
    }
#pragma unroll
    for (int os = 0; os < 4; os++)
#pragma unroll
    for (int r = 0; r < 4; r++) {
        int o = o0 + os * 16 + q * 4 + r;
        float bias = zb[o];
        float sr = 0.f, qr = 0.f;
#pragma unroll
        for (int nt = 0; nt < 4; nt++) {
            float v = acc[os][nt][r] + bias;
            wy[((size_t)bb * C_ + o) * N_ + n0 + nt * 16 + l16] = (f16)v;
            sr += v; qr += v * v;
        }
#pragma unroll
        for (int off = 1; off < 16; off <<= 1) {
            sr += __shfl_xor(sr, off);
            qr += __shfl_xor(qr, off);
        }
        if (l16 == 0) {
            psum[(o * 2 + 0) * 256 + id] = sr;
            psum[(o * 2 + 1) * 256 + id] = qr;
        }
    }
}

// ---------------- reduce psum -> ssum/ssq ----------------
__global__ void k_red(const float* __restrict__ psum, float* __restrict__ ssum,
                      float* __restrict__ ssq) {
    int b = blockIdx.x;                   // 0: ssum, 1: ssq
    int o = threadIdx.x;
    const float* src = psum + (o * 2 + b) * 256;
    float s = 0.f;
    for (int k = 0; k < 64; k++) {
        float4 v = reinterpret_cast<const float4*>(src)[k];
        s += v.x + v.y + v.z + v.w;
    }
    (b == 0 ? ssum : ssq)[o] = s;
}

// ---------------- pass 5: BN (stats inline) + residual ----------------
__global__ void k_final(const f16* __restrict__ wy, const float* __restrict__ x,
                        const float* __restrict__ ssum, const float* __restrict__ ssq,
                        const float* __restrict__ gamma, const float* __restrict__ beta,
                        float* __restrict__ out) {
    int p = blockIdx.x * 256 + threadIdx.x;           // 512K groups of 8
    int c = (p >> 9) & 255;
    const float inv = 1.0f / 16384.0f;
    float mean = ssum[c] * inv;
    float var = ssq[c] * inv - mean * mean;
    float s = gamma[c] * rsqrtf(var + 1e-5f);
    float h = beta[c] - mean * s;
    f16x8 wv = reinterpret_cast<const f16x8*>(wy)[p];
    float4 x0 = reinterpret_cast<const float4*>(x)[2 * p];
    float4 x1 = reinterpret_cast<const float4*>(x)[2 * p + 1];
    float4 o0, o1;
    o0.x = (float)wv[0] * s + h + x0.x;
    o0.y = (float)wv[1] * s + h + x0.y;
    o0.z = (float)wv[2] * s + h + x0.z;
    o0.w = (float)wv[3] * s + h + x0.w;
    o1.x = (float)wv[4] * s + h + x1.x;
    o1.y = (float)wv[5] * s + h + x1.y;
    o1.z = (float)wv[6] * s + h + x1.z;
    o1.w = (float)wv[7] * s + h + x1.w;
    reinterpret_cast<float4*>(out)[2 * p] = o0;
    reinterpret_cast<float4*>(out)[2 * p + 1] = o1;
}

extern "C" void kernel_launch(void* const* d_in, const int* in_sizes, int n_in,
                              void* d_out, int out_size, void* d_ws, size_t ws_size,
                              hipStream_t stream) {
    const float* x     = (const float*)d_in[0];
    const float* gw    = (const float*)d_in[1];
    const float* gb    = (const float*)d_in[2];
    const float* tw    = (const float*)d_in[3];
    const float* tbv   = (const float*)d_in[4];
    const float* pw    = (const float*)d_in[5];
    const float* pb    = (const float*)d_in[6];
    const float* zw    = (const float*)d_in[7];
    const float* zb    = (const float*)d_in[8];
    const float* gamma = (const float*)d_in[9];
    const float* beta  = (const float*)d_in[10];

    char* ws = (char*)d_ws;
    f16* thetaT = (f16*)(ws + OFF_THETA);
    f16* phiT   = (f16*)(ws + OFF_PHI);
    f16* gC     = (f16*)(ws + OFF_G);
    f16* yP     = (f16*)(ws + OFF_YP);
    f16* wy     = (f16*)(ws + OFF_WY);
    f16* wcvt   = (f16*)(ws + OFF_WCVT);
    float* md   = (float*)(ws + OFF_MD);
    float* ps   = (float*)(ws + OFF_PS);
    float* psum = (float*)(ws + OFF_PSUM);
    float* ssum = (float*)(ws + OFF_SSUM);
    float* ssq  = (float*)(ws + OFF_SSQ);

    k_init<<<512, 256, 0, stream>>>(gw, tw, pw, zw, wcvt);
    k_proj<<<512, 256, 0, stream>>>(x, wcvt, gb, tbv, pb, thetaT, phiT, gC);
    k_cols<<<2048, 256, 0, stream>>>(thetaT, phiT, ps);
    k_colmerge<<<64, 256, 0, stream>>>(ps, md);
    k_attn<<<256, 512, 0, stream>>>(thetaT, phiT, gC, md, yP);
    k_wz<<<256, 256, 0, stream>>>(wcvt + 3 * 32768, yP, zb, wy, psum);
    k_red<<<2, 256, 0, stream>>>(psum, ssum, ssq);
    k_final<<<2048, 256, 0, stream>>>(wy, x, ssum, ssq, gamma, beta, (float*)d_out);
}

// Round 7
// 185.130 us; speedup vs baseline: 1.1034x; 1.0679x over previous
//
#include <hip/hip_runtime.h>

// NonLocalBlock: B=4, C=256, Ci=128, H=W=64, N=4096.
// R16: launch-count consolidation. R15 post-mortem: k_attn ~40us (out of
// top-5; harness 256MiB fill at 44us dominates), ~24us of inter-dispatch
// gaps across 8 kernels is now a top lever. (1) k_colmerge folded into
// k_attn prologue: block computes its 1024-entry mdL slice from ps directly
// (16x-redundant 64KB L2 reads, hidden under tile staging latency); md
// array + kernel gone. (2) k_red folded into k_final: each block serves one
// channel, reduces psum itself (shuffle+LDS). k_attn loop body, k_cols,
// k_proj, k_wz unchanged from R15.

#define B_  4
#define C_  256
#define CI  128
#define N_  4096
#define NB  (B_*N_)     // 16384
#define ISPLIT 16
#define MB_ (1u<<20)
#define LOG2E 1.442695041f

typedef _Float16 f16;
typedef f16   f16x8 __attribute__((ext_vector_type(8)));
typedef f16   f16x4 __attribute__((ext_vector_type(4)));
typedef float f32x4 __attribute__((ext_vector_type(4)));
typedef float f32x16 __attribute__((ext_vector_type(16)));
typedef unsigned u32x2 __attribute__((ext_vector_type(2)));
typedef unsigned u32x4v __attribute__((ext_vector_type(4)));

#define MFMA(a,b,c)   __builtin_amdgcn_mfma_f32_16x16x32_f16(a,b,c,0,0,0)
#define MFMA32(a,b,c) __builtin_amdgcn_mfma_f32_32x32x16_f16(a,b,c,0,0,0)

// async global->LDS, 16B per lane; LDS dest = wave-uniform base + lane*16
#define GLD16(g, lp) __builtin_amdgcn_global_load_lds( \
    (const __attribute__((address_space(1))) void*)(g), \
    (__attribute__((address_space(3))) void*)(lp), 16, 0, 0)

// ---- workspace byte offsets (~30 MB) ----
#define OFF_THETA  0                 // f16 [B][N][CI]  4 MB (pre-scaled by log2e)
#define OFF_PHI    (4u*MB_)          // f16 [B][N][CI]  4 MB
#define OFF_G      (8u*MB_)          // f16 [B][CI][N]  4 MB
#define OFF_YP     (12u*MB_)         // f16 [4][B][N][CI]  16 MB (j-quarter partials)
#define OFF_WY     0                 // f16 [B][C][N] 8 MB — overlays theta+phi (dead by k_wz)
#define OFF_PS     (28u*MB_)                  // f32 [ISPLIT][NB]  1 MB
#define OFF_PSUM   (OFF_PS + ISPLIT*NB*4)     // f32 [256][2][256]  512 KB
#define OFF_WCVT   (OFF_PSUM + 524288)        // f16 weights g,t,p,z  256 KB
#define PSZ ((size_t)B_*N_*CI)

// ---------------- init: weight cvt f32->f16 ----------------
__global__ void k_init(const float* gw, const float* tw, const float* pw,
                       const float* zw, f16* wcvt) {
    int i = blockIdx.x * 256 + threadIdx.x;          // 0..131071
    const float* s;
    int which = i >> 15;
    if (which == 0) s = gw; else if (which == 1) s = tw;
    else if (which == 2) s = pw; else s = zw;
    wcvt[i] = (f16)s[i & 32767];
}

// ---------------- fused 1x1-conv projections (all 3, one x read) ----------------
__global__ __launch_bounds__(256) void k_proj(
        const float* __restrict__ x, const f16* __restrict__ wcvt,
        const float* __restrict__ gb, const float* __restrict__ tb,
        const float* __restrict__ pb,
        f16* __restrict__ thetaT, f16* __restrict__ phiT, f16* __restrict__ gC) {
    __shared__ __align__(16) f16 xT[32 * 264];       // [n][c], stride 264
    int bb = blockIdx.x >> 7;
    int n0 = (blockIdx.x & 127) * 32;
    int t = threadIdx.x;

    const float* xb = x + (size_t)bb * C_ * N_;
    for (int rep = 0; rep < 8; rep++) {
        int lin = rep * 256 + t;
        int c = lin >> 3, np = (lin & 7) * 4;
        float4 v = *reinterpret_cast<const float4*>(xb + c * N_ + n0 + np);
        xT[(np + 0) * 264 + c] = (f16)v.x;
        xT[(np + 1) * 264 + c] = (f16)v.y;
        xT[(np + 2) * 264 + c] = (f16)v.z;
        xT[(np + 3) * 264 + c] = (f16)v.w;
    }
    __syncthreads();

    int w = t >> 6, l16 = t & 15, q = (t & 63) >> 4;
    int ci0 = w * 32;
    for (int proj = 0; proj < 3; proj++) {
        const f16* W0 = wcvt + proj * 32768;         // [128][256] f16 row-major
        f32x4 acc[2][2] = {};
        for (int kk = 0; kk < 8; kk++) {
            f16x8 a0 = *reinterpret_cast<const f16x8*>(W0 + (ci0 + l16) * 256 + kk * 32 + q * 8);
            f16x8 a1 = *reinterpret_cast<const f16x8*>(W0 + (ci0 + 16 + l16) * 256 + kk * 32 + q * 8);
#pragma unroll
            for (int nt = 0; nt < 2; nt++) {
                f16x8 bv = *reinterpret_cast<const f16x8*>(&xT[(nt * 16 + l16) * 264 + kk * 32 + q * 8]);
                acc[0][nt] = MFMA(a0, bv, acc[0][nt]);
                acc[1][nt] = MFMA(a1, bv, acc[1][nt]);
            }
        }
        const float* bias = (proj == 0) ? gb : (proj == 1) ? tb : pb;
        float scl = (proj == 1) ? LOG2E : 1.0f;      // fold ln2 into theta
#pragma unroll
        for (int a = 0; a < 2; a++) {
#pragma unroll
            for (int nt = 0; nt < 2; nt++) {
                int n = n0 + nt * 16 + l16;
                int cib = ci0 + a * 16 + q * 4;
                if (proj == 0) {
#pragma unroll
                    for (int r = 0; r < 4; r++)
                        gC[((size_t)bb * CI + cib + r) * N_ + n] = (f16)(acc[a][nt][r] + bias[cib + r]);
                } else {
                    f16x4 v4;
#pragma unroll
                    for (int r = 0; r < 4; r++)
                        v4[r] = (f16)((acc[a][nt][r] + bias[cib + r]) * scl);
                    f16* dst = (proj == 1 ? thetaT : phiT) + ((size_t)bb * N_ + n) * CI + cib;
                    *reinterpret_cast<f16x4*>(dst) = v4;
                }
            }
        }
    }
}

// ---------------- pass 2: column exp-sums (32x32 swapped, lane-local j) ------
// grid 2048 = bb(4) x jb(32) x isp(16); i-slice 256 = 4 staged tiles of 64.
__global__ __launch_bounds__(256, 4) void k_cols(
        const f16* __restrict__ thetaT, const f16* __restrict__ phiT,
        float* __restrict__ ps) {
    __shared__ __align__(16) f16 thS[2][64 * 128];
    int id = blockIdx.x;                 // 2048
    int isp = id & 15, jb = (id >> 4) & 31, bb = id >> 9;
    int t = threadIdx.x, w = t >> 6, l = t & 63;
    int l31 = l & 31, hi = l >> 5;
    int jw = jb * 128 + w * 32 + l31;    // this lane's j column

    // phi B-frags: B[k][n=j], lane n=l31, k = kk*16 + hi*8 + e
    f16x8 pf[8];
    const f16* pb = phiT + ((size_t)bb * N_ + jw) * CI + hi * 8;
#pragma unroll
    for (int kk = 0; kk < 8; kk++)
        pf[kk] = *reinterpret_cast<const f16x8*>(pb + kk * 16);

    const f16* thB = thetaT + ((size_t)bb * N_ + isp * 256) * CI;
    auto stage = [&](int bf, int it0) {
#pragma unroll
        for (int r = 0; r < 4; r++) {
            int p = r * 256 + w * 64 + l;
            int pi = p >> 4, pu = (p & 15) ^ (pi & 15);
            const char* ga = (const char*)(thB + (size_t)(it0 + pi) * CI) + pu * 16;
            GLD16(ga, &thS[bf][(r * 256 + w * 64) * 8]);
        }
    };

    float s = 0.f;
    stage(0, 0);
    __syncthreads();
    for (int it = 0; it < 4; it++) {
        int bf = it & 1;
        if (it + 1 < 4) stage(bf ^ 1, (it + 1) * 64);
#pragma unroll
        for (int it2 = 0; it2 < 2; it2++) {
            f16x8 av[8];
#pragma unroll
            for (int kk = 0; kk < 8; kk++)
                av[kk] = *reinterpret_cast<const f16x8*>(
                    &thS[bf][(it2 * 32 + l31) * 128 + (((kk * 2 + hi) ^ (l31 & 15)) * 8)]);
            f32x16 f = {};
            __builtin_amdgcn_s_setprio(1);
#pragma unroll
            for (int kk = 0; kk < 8; kk++)
                f = MFMA32(av[kk], pf[kk], f);
            __builtin_amdgcn_s_setprio(0);
#pragma unroll
            for (int r = 0; r < 16; r++)
                s += __builtin_amdgcn_exp2f(f[r]);
        }
        __syncthreads();
    }
    s += __shfl_xor(s, 32);
    if (hi == 0)
        ps[isp * NB + bb * N_ + jw] = s;
}

// ---------------- pass 3: y = softmax(f) @ g  (counted-vmcnt 3-buffer) ------
// grid 256 = jq(4) x bb(4) x ib(16); block = 512 threads (8 waves) on 256 i.
// Wave w: js = w>>2 (32-j half), iw = w&3 (64-i block, 2 i-sets of 32).
// Prologue folds k_colmerge: mdL[j] = -log2(sum_isp ps) computed in-block
// (thread t covers j = jbase+t, jbase+512+t), hidden under tile staging.
// Schedule: stage(t+2) -> compute(t) -> s_waitcnt vmcnt(4) -> raw s_barrier.
__global__ __launch_bounds__(512, 2) void k_attn(
        const f16* __restrict__ thetaT, const f16* __restrict__ phiT,
        const f16* __restrict__ gC, const float* __restrict__ ps,
        f16* __restrict__ yP) {
    __shared__ __align__(16) char smem[102400];      // 3x(16+16) KB tiles + 4 KB md
    f16 (*phiS)[64 * 128] = (f16(*)[64 * 128])smem;            // 3 x 16 KB [j][ci]
    f16 (*gS)[128 * 64]   = (f16(*)[128 * 64])(smem + 49152);  // 3 x 16 KB [ci][j]
    float* mdL = (float*)(smem + 98304);                       // [1024] -log2 D

    int jq = blockIdx.x & 3;
    int ib = blockIdx.x >> 2;          // 0..63
    int bb = ib >> 4;
    int i0 = (ib & 15) * 256;
    int t = threadIdx.x, w = t >> 6, l = t & 63;
    int l31 = l & 31, hi = l >> 5;
    int js = w >> 2, iw = w & 3;
    int jbase = jq * 1024;

    // ---- fold of k_colmerge: mdL slice from ps (before staging issues) ----
    {
        const float* pp = ps + bb * N_ + jbase;
        float s0 = 0.f, s1 = 0.f;
#pragma unroll
        for (int isp = 0; isp < ISPLIT; isp++) {
            s0 += pp[isp * NB + t];
            s1 += pp[isp * NB + t + 512];
        }
        mdL[t]       = -__log2f(s0);
        mdL[t + 512] = -__log2f(s1);
    }

    // theta B-fragments, 2 i-sets of 32: B[n=i][k]; lane n=l31, k=hi*8+e
    f16x8 ta[2][8];
#pragma unroll
    for (int is = 0; is < 2; is++) {
        const f16* tb = thetaT + ((size_t)bb * N_ + i0 + iw * 64 + is * 32 + l31) * CI + hi * 8;
#pragma unroll
        for (int kk = 0; kk < 8; kk++)
            ta[is][kk] = *reinterpret_cast<const f16x8*>(tb + kk * 16);
    }

    const f16* phiB = phiT + (size_t)bb * N_ * CI;
    const f16* gB   = gC   + (size_t)bb * CI * N_;

    // 512 threads: 2 GLD16 pairs per thread cover 64x128 phi + 128x64 g
    auto stage = [&](int bf, int j0g) {
#pragma unroll
        for (int r = 0; r < 2; r++) {
            int p = r * 512 + t;
            int ub = (r * 512 + w * 64) * 8;          // wave-uniform LDS base (f16)
            int pj = p >> 4, pu = (p & 15) ^ (pj & 15);
            const char* ga = (const char*)(phiB + (size_t)(j0g + pj) * CI) + pu * 16;
            GLD16(ga, &phiS[bf][ub]);
            int pc = p >> 3, pu2 = (p & 7) ^ (pc & 7);
            const char* ga2 = (const char*)(gB + (size_t)pc * N_ + j0g) + pu2 * 16;
            GLD16(ga2, &gS[bf][ub]);
        }
    };

    stage(0, jbase);
    stage(1, jbase + 64);
    asm volatile("s_waitcnt vmcnt(4) lgkmcnt(0)" ::: "memory");
    __builtin_amdgcn_s_barrier();

    f32x16 yacc[2][4] = {};              // [iset][cs]: y[i 32][ci = cs*32+l31]
    for (int jt = 0; jt < 16; jt++) {
        int bf = jt % 3;
        if (jt + 2 < 16) stage((jt + 2) % 3, jbase + (jt + 2) * 64);

        // facc init = -log2(D) from LDS (j-dependent only; same for both i-sets)
        f32x16 facc[2];
#pragma unroll
        for (int c = 0; c < 4; c++) {
            f32x4 v = *reinterpret_cast<const f32x4*>(
                &mdL[jt * 64 + js * 32 + c * 8 + hi * 4]);
            facc[0][c * 4 + 0] = v[0]; facc[0][c * 4 + 1] = v[1];
            facc[0][c * 4 + 2] = v[2]; facc[0][c * 4 + 3] = v[3];
            facc[1][c * 4 + 0] = v[0]; facc[1][c * 4 + 1] = v[1];
            facc[1][c * 4 + 2] = v[2]; facc[1][c * 4 + 3] = v[3];
        }

        // QK: each pv read feeds both i-sets
        __builtin_amdgcn_s_setprio(1);
#pragma unroll
        for (int kk = 0; kk < 8; kk++) {
            f16x8 pv = *reinterpret_cast<const f16x8*>(
                &phiS[bf][(js * 32 + l31) * 128 + (((kk * 2 + hi) ^ (l31 & 15)) * 8)]);
            facc[0] = MFMA32(pv, ta[0][kk], facc[0]);
            facc[1] = MFMA32(pv, ta[1][kk], facc[1]);
        }
        __builtin_amdgcn_s_setprio(0);

        // softmax (exp2) + in-register relayout; each gv read feeds both i-sets
#pragma unroll
        for (int ch = 0; ch < 2; ch++) {
            f16x8 wfr[2];
#pragma unroll
            for (int is = 0; is < 2; is++) {
                float e0 = __builtin_amdgcn_exp2f(facc[is][ch * 8 + 0]);
                float e1 = __builtin_amdgcn_exp2f(facc[is][ch * 8 + 1]);
                float e2 = __builtin_amdgcn_exp2f(facc[is][ch * 8 + 2]);
                float e3 = __builtin_amdgcn_exp2f(facc[is][ch * 8 + 3]);
                float e4 = __builtin_amdgcn_exp2f(facc[is][ch * 8 + 4]);
                float e5 = __builtin_amdgcn_exp2f(facc[is][ch * 8 + 5]);
                float e6 = __builtin_amdgcn_exp2f(facc[is][ch * 8 + 6]);
                float e7 = __builtin_amdgcn_exp2f(facc[is][ch * 8 + 7]);
                unsigned p01 = __builtin_bit_cast(unsigned, __builtin_amdgcn_cvt_pkrtz(e0, e1));
                unsigned p23 = __builtin_bit_cast(unsigned, __builtin_amdgcn_cvt_pkrtz(e2, e3));
                unsigned p45 = __builtin_bit_cast(unsigned, __builtin_amdgcn_cvt_pkrtz(e4, e5));
                unsigned p67 = __builtin_bit_cast(unsigned, __builtin_amdgcn_cvt_pkrtz(e6, e7));
                u32x2 s0 = __builtin_amdgcn_permlane32_swap(p01, p45, false, false);
                u32x2 s1 = __builtin_amdgcn_permlane32_swap(p23, p67, false, false);
                u32x4v wu = {s0[0], s1[0], s0[1], s1[1]};
                wfr[is] = __builtin_bit_cast(f16x8, wu);   // A[m=i=l31][k=hi*8+e]
            }
            int jc = js * 2 + ch;                          // 16-j chunk index
            __builtin_amdgcn_s_setprio(1);
#pragma unroll
            for (int cs = 0; cs < 4; cs++) {
                f16x8 gv = *reinterpret_cast<const f16x8*>(
                    &gS[bf][(cs * 32 + l31) * 64 + (((jc * 2 + hi) ^ (l31 & 7)) * 8)]);
                yacc[0][cs] = MFMA32(wfr[0], gv, yacc[0][cs]);
                yacc[1][cs] = MFMA32(wfr[1], gv, yacc[1][cs]);
            }
            __builtin_amdgcn_s_setprio(0);
        }

        // counted wait: keep tile t+2 in flight (4 loads/wave); drain at tail
        if (jt < 14) { asm volatile("s_waitcnt vmcnt(4)" ::: "memory"); }
        else         { asm volatile("s_waitcnt vmcnt(0)" ::: "memory"); }
        __builtin_amdgcn_s_barrier();
    }

    // ---- cross-pair reduction: js=1 partials -> js=0 waves, per i-set ----
    float* red = (float*)smem;            // 64 KB overlay (buffers dead)
#pragma unroll
    for (int is = 0; is < 2; is++) {
        __syncthreads();
        if (js == 1) {
#pragma unroll
            for (int cs = 0; cs < 4; cs++)
#pragma unroll
                for (int rq = 0; rq < 4; rq++) {
                    f32x4 v;
                    v[0] = yacc[is][cs][rq * 4 + 0];
                    v[1] = yacc[is][cs][rq * 4 + 1];
                    v[2] = yacc[is][cs][rq * 4 + 2];
                    v[3] = yacc[is][cs][rq * 4 + 3];
                    *reinterpret_cast<f32x4*>(&red[((iw * 4 + cs) * 4 + rq) * 256 + l * 4]) = v;
                }
        }
        __syncthreads();
        if (js == 0) {
#pragma unroll
            for (int cs = 0; cs < 4; cs++)
#pragma unroll
                for (int rq = 0; rq < 4; rq++) {
                    f32x4 v = *reinterpret_cast<const f32x4*>(
                        &red[((iw * 4 + cs) * 4 + rq) * 256 + l * 4]);
                    yacc[is][cs][rq * 4 + 0] += v[0];
                    yacc[is][cs][rq * 4 + 1] += v[1];
                    yacc[is][cs][rq * 4 + 2] += v[2];
                    yacc[is][cs][rq * 4 + 3] += v[3];
                }
        }
    }
    __syncthreads();

    // ---- epilogue (js=0 waves): transpose via per-wave LDS, store yP ----
    if (js == 0) {
        f16* yw = (f16*)smem + iw * (32 * 136);
#pragma unroll
        for (int is = 0; is < 2; is++) {
#pragma unroll
            for (int cs = 0; cs < 4; cs++)
#pragma unroll
                for (int r = 0; r < 16; r++)
                    yw[((r & 3) + 8 * (r >> 2) + 4 * hi) * 136 + cs * 32 + l31] =
                        (f16)yacc[is][cs][r];
            f16* yo = yP + (size_t)jq * PSZ + ((size_t)bb * N_ + i0 + iw * 64 + is * 32) * CI;
            __builtin_amdgcn_s_waitcnt(0);   // lgkm: yw writes visible to own wave
#pragma unroll
            for (int rr = 0; rr < 8; rr++) {
                int chunk = rr * 64 + l;
                int il = chunk >> 4, u = chunk & 15;
                *reinterpret_cast<f16x8*>(yo + il * CI + u * 8) =
                    *reinterpret_cast<const f16x8*>(&yw[il * 136 + u * 8]);
            }
            __builtin_amdgcn_s_waitcnt(0);   // drain reads before is=1 overwrites yw
        }
    }
}

// ---------------- pass 4: w_y = wz @ (sum of y partials) + b ----------------
// grid 256: block = bb(4) x nb(64 n-tiles of 64); reads its yP slice ONCE,
// computes all 256 output channels; per-block channel partials -> psum.
__global__ __launch_bounds__(256) void k_wz(
        const f16* __restrict__ wzc, const f16* __restrict__ yP,
        const float* __restrict__ zb, f16* __restrict__ wy,
        float* __restrict__ psum) {
    int id = blockIdx.x;                  // 256
    int nb = id & 63, bb = id >> 6;
    int t = threadIdx.x, w = t >> 6, l16 = t & 15, q = (t & 63) >> 4;
    int o0 = w * 64, n0 = nb * 64;
    f32x4 acc[4][4] = {};                 // [os][nt]
#pragma unroll
    for (int kk = 0; kk < 4; kk++) {
        f16x8 bv[4];
#pragma unroll
        for (int nt = 0; nt < 4; nt++) {
            size_t yi = ((size_t)bb * N_ + n0 + nt * 16 + l16) * CI + kk * 32 + q * 8;
            f16x8 b0 = *reinterpret_cast<const f16x8*>(yP + yi);
            f16x8 b1 = *reinterpret_cast<const f16x8*>(yP + PSZ + yi);
            f16x8 b2 = *reinterpret_cast<const f16x8*>(yP + 2 * PSZ + yi);
            f16x8 b3 = *reinterpret_cast<const f16x8*>(yP + 3 * PSZ + yi);
            bv[nt] = (b0 + b1) + (b2 + b3);
        }
#pragma unroll
        for (int os = 0; os < 4; os++) {
            f16x8 av = *reinterpret_cast<const f16x8*>(
                wzc + (o0 + os * 16 + l16) * CI + kk * 32 + q * 8);
#pragma unroll
            for (int nt = 0; nt < 4; nt++)
                acc[os][nt] = MFMA(av, bv[nt], acc[os][nt]);
        }
    }
#pragma unroll
    for (int os = 0; os < 4; os++)
#pragma unroll
    for (int r = 0; r < 4; r++) {
        int o = o0 + os * 16 + q * 4 + r;
        float bias = zb[o];
        float sr = 0.f, qr = 0.f;
#pragma unroll
        for (int nt = 0; nt < 4; nt++) {
            float v = acc[os][nt][r] + bias;
            wy[((size_t)bb * C_ + o) * N_ + n0 + nt * 16 + l16] = (f16)v;
            sr += v; qr += v * v;
        }
#pragma unroll
        for (int off = 1; off < 16; off <<= 1) {
            sr += __shfl_xor(sr, off);
            qr += __shfl_xor(qr, off);
        }
        if (l16 == 0) {
            psum[(o * 2 + 0) * 256 + id] = sr;
            psum[(o * 2 + 1) * 256 + id] = qr;
        }
    }
}

// ---------------- pass 5: BN stats (fold of k_red) + BN + residual ----------
// grid 2048 x 256; each block serves ONE channel c = blockIdx>>3 (p>>9 is
// block-uniform), reduces its psum rows in-block (shuffle + LDS), then
// normalizes + residual exactly as before.
__global__ void k_final(const f16* __restrict__ wy, const float* __restrict__ x,
                        const float* __restrict__ psum,
                        const float* __restrict__ gamma, const float* __restrict__ beta,
                        float* __restrict__ out) {
    __shared__ float s8[8];
    int t = threadIdx.x;
    int p = blockIdx.x * 256 + t;                     // 512K groups of 8
    int c = (p >> 9) & 255;                           // block-uniform
    float sr = psum[(c * 2 + 0) * 256 + t];
    float qr = psum[(c * 2 + 1) * 256 + t];
#pragma unroll
    for (int off = 1; off < 64; off <<= 1) {
        sr += __shfl_xor(sr, off);
        qr += __shfl_xor(qr, off);
    }
    int w = t >> 6;
    if ((t & 63) == 0) { s8[w * 2] = sr; s8[w * 2 + 1] = qr; }
    __syncthreads();
    float ssum = s8[0] + s8[2] + s8[4] + s8[6];
    float ssq  = s8[1] + s8[3] + s8[5] + s8[7];

    const float inv = 1.0f / 16384.0f;
    float mean = ssum * inv;
    float var = ssq * inv - mean * mean;
    float s = gamma[c] * rsqrtf(var + 1e-5f);
    float h = beta[c] - mean * s;
    f16x8 wv = reinterpret_cast<const f16x8*>(wy)[p];
    float4 x0 = reinterpret_cast<const float4*>(x)[2 * p];
    float4 x1 = reinterpret_cast<const float4*>(x)[2 * p + 1];
    float4 o0, o1;
    o0.x = (float)wv[0] * s + h + x0.x;
    o0.y = (float)wv[1] * s + h + x0.y;
    o0.z = (float)wv[2] * s + h + x0.z;
    o0.w = (float)wv[3] * s + h + x0.w;
    o1.x = (float)wv[4] * s + h + x1.x;
    o1.y = (float)wv[5] * s + h + x1.y;
    o1.z = (float)wv[6] * s + h + x1.z;
    o1.w = (float)wv[7] * s + h + x1.w;
    reinterpret_cast<float4*>(out)[2 * p] = o0;
    reinterpret_cast<float4*>(out)[2 * p + 1] = o1;
}

extern "C" void kernel_launch(void* const* d_in, const int* in_sizes, int n_in,
                              void* d_out, int out_size, void* d_ws, size_t ws_size,
                              hipStream_t stream) {
    const float* x     = (const float*)d_in[0];
    const float* gw    = (const float*)d_in[1];
    const float* gb    = (const float*)d_in[2];
    const float* tw    = (const float*)d_in[3];
    const float* tbv   = (const float*)d_in[4];
    const float* pw    = (const float*)d_in[5];
    const float* pb    = (const float*)d_in[6];
    const float* zw    = (const float*)d_in[7];
    const float* zb    = (const float*)d_in[8];
    const float* gamma = (const float*)d_in[9];
    const float* beta  = (const float*)d_in[10];

    char* ws = (char*)d_ws;
    f16* thetaT = (f16*)(ws + OFF_THETA);
    f16* phiT   = (f16*)(ws + OFF_PHI);
    f16* gC     = (f16*)(ws + OFF_G);
    f16* yP     = (f16*)(ws + OFF_YP);
    f16* wy     = (f16*)(ws + OFF_WY);
    f16* wcvt   = (f16*)(ws + OFF_WCVT);
    float* ps   = (float*)(ws + OFF_PS);
    float* psum = (float*)(ws + OFF_PSUM);

    k_init<<<512, 256, 0, stream>>>(gw, tw, pw, zw, wcvt);
    k_proj<<<512, 256, 0, stream>>>(x, wcvt, gb, tbv, pb, thetaT, phiT, gC);
    k_cols<<<2048, 256, 0, stream>>>(thetaT, phiT, ps);
    k_attn<<<256, 512, 0, stream>>>(thetaT, phiT, gC, ps, yP);
    k_wz<<<256, 256, 0, stream>>>(wcvt + 3 * 32768, yP, zb, wy, psum);
    k_final<<<2048, 256, 0, stream>>>(wy, x, psum, gamma, beta, (float*)d_out);
}